// Round 3
// baseline (1239.205 us; speedup 1.0000x reference)
//
#include <hip/hip_runtime.h>
#include <hip/hip_bf16.h>

// NodeNetwork: mi = segsum(ea*x[row] -> col), mo = segsum(ea*x[col] -> row)
// out = tanh(tanh([mi|mo|x] @ W1 + b1) @ W2 + b2)
// N=100000, D=32, O=64, E=1600000
//
// R3: coarse-bucket counting sort (64 keys/bucket -> dense tickets -> L2
// write combining) + per-bucket LDS accumulation (no per-key scan/gather).
// R2 profile: per-key scatter had 8x write amplification (198MB HBM writes
// for 25.6MB payload) at 670 GB/s effective -> 297 us.

#define DFEAT 32
#define OFEAT 64
#define KPB   64      // keys per bucket (key = 2*node + dir)

// ---- 1. bucket histogram ----
__global__ __launch_bounds__(256) void hist_kernel(
    const int* __restrict__ ei, int* __restrict__ bcnt, int E)
{
    int e = blockIdx.x * 256 + threadIdx.x;
    if (e >= E) return;
    int r = ei[e];
    int c = ei[E + e];
    atomicAdd(&bcnt[(2 * c) >> 6], 1);       // mi record -> bucket of key 2c
    atomicAdd(&bcnt[(2 * r + 1) >> 6], 1);   // mo record -> bucket of key 2r+1
}

// ---- 2a. per-block reduce (256 elems/block) ----
__global__ __launch_bounds__(256) void scan_reduce(
    const int* __restrict__ cnt, int* __restrict__ bsum, int M)
{
    __shared__ int s[256];
    int i = blockIdx.x * 256 + threadIdx.x;
    s[threadIdx.x] = (i < M) ? cnt[i] : 0;
    __syncthreads();
    for (int st = 128; st > 0; st >>= 1) {
        if (threadIdx.x < st) s[threadIdx.x] += s[threadIdx.x + st];
        __syncthreads();
    }
    if (threadIdx.x == 0) bsum[blockIdx.x] = s[0];
}

// ---- 2b. single-block exclusive scan of block sums ----
__global__ __launch_bounds__(1024) void scan_bsums(int* __restrict__ bsum, int nb)
{
    __shared__ int s[1024];
    int t = threadIdx.x;
    s[t] = (t < nb) ? bsum[t] : 0;
    __syncthreads();
    for (int off = 1; off < 1024; off <<= 1) {
        int v = (t >= off) ? s[t - off] : 0;
        __syncthreads();
        s[t] += v;
        __syncthreads();
    }
    if (t < nb) bsum[t] = (t == 0) ? 0 : s[t - 1];
}

// ---- 2c. per-block scan + block prefix -> off, cur ----
__global__ __launch_bounds__(256) void scan_final(
    const int* __restrict__ cnt, const int* __restrict__ bsum,
    int* __restrict__ off, int* __restrict__ cur, int M)
{
    __shared__ int s[256];
    int i = blockIdx.x * 256 + threadIdx.x;
    int v = (i < M) ? cnt[i] : 0;
    s[threadIdx.x] = v;
    __syncthreads();
    for (int o = 1; o < 256; o <<= 1) {
        int u = (threadIdx.x >= o) ? s[threadIdx.x - o] : 0;
        __syncthreads();
        s[threadIdx.x] += u;
        __syncthreads();
    }
    int excl = s[threadIdx.x] - v + bsum[blockIdx.x];
    if (i < M) { off[i] = excl; cur[i] = excl; }
}

// ---- 3. scatter packed records into bucket regions (dense tickets) ----
// record.x = src | (lkey << 17), record.y = attr bits
__global__ __launch_bounds__(256) void scatter_kernel(
    const int* __restrict__ ei, const float* __restrict__ ea,
    int* __restrict__ bcur, int2* __restrict__ pay, int E)
{
    int e = blockIdx.x * 256 + threadIdx.x;
    if (e >= E) return;
    int r = ei[e];
    int c = ei[E + e];
    int ab = __float_as_int(ea[e]);
    int k0 = 2 * c;                              // mi: src = r
    int p0 = atomicAdd(&bcur[k0 >> 6], 1);
    pay[p0] = make_int2(r | ((k0 & 63) << 17), ab);
    int k1 = 2 * r + 1;                          // mo: src = c
    int p1 = atomicAdd(&bcur[k1 >> 6], 1);
    pay[p1] = make_int2(c | ((k1 & 63) << 17), ab);
}

// ---- 4. per-bucket LDS accumulate + coalesced writeout ----
__global__ __launch_bounds__(256) void bucket_accum(
    const float* __restrict__ x,
    const int* __restrict__ boff, const int* __restrict__ bcnt,
    const int2* __restrict__ pay,
    float* __restrict__ mi, float* __restrict__ mo, int NK)
{
    __shared__ float acc[KPB * DFEAT];           // 8 KB
    int b = blockIdx.x;
    for (int i = threadIdx.x; i < KPB * DFEAT; i += 256) acc[i] = 0.0f;
    __syncthreads();

    int base = boff[b];
    int end  = base + bcnt[b];
    int sub  = threadIdx.x >> 5;                 // 0..7 (half-wave id)
    int feat = threadIdx.x & 31;

    for (int i = base + sub; i < end; i += 8) {
        int2 p = pay[i];                         // broadcast within half-wave
        int src  = p.x & 0x1FFFF;
        int lkey = (p.x >> 17) & 63;
        float a  = __int_as_float(p.y);
        float xv = x[(long long)src * DFEAT + feat];   // coalesced 128B
        atomicAdd(&acc[lkey * DFEAT + feat], a * xv);  // ds_add, no conflicts
    }
    __syncthreads();

    int key0 = b * KPB;
    for (int i = threadIdx.x; i < KPB * DFEAT; i += 256) {
        int gk = key0 + (i >> 5);
        if (gk < NK) {
            int node = gk >> 1;
            float v = acc[i];
            if (gk & 1) mo[(long long)node * DFEAT + (i & 31)] = v;
            else        mi[(long long)node * DFEAT + (i & 31)] = v;
        }
    }
}

// ---- R1 fallback: direct atomic scatter (ws too small) ----
__global__ __launch_bounds__(256) void edge_scatter_kernel(
    const float* __restrict__ x, const int* __restrict__ ei,
    const float* __restrict__ ea,
    float* __restrict__ mi, float* __restrict__ mo, int E)
{
    long long tid = (long long)blockIdx.x * blockDim.x + threadIdx.x;
    long long total = (long long)E * 8;
    if (tid >= total) return;
    int e = (int)(tid >> 3);
    int q = (int)(tid & 7);
    int r = ei[e];
    int c = ei[E + e];
    float a = ea[e];
    const float4* x4 = (const float4*)x;
    float4 xr = x4[(long long)r * 8 + q];
    float4 xc = x4[(long long)c * 8 + q];
    float* mip = mi + (long long)c * DFEAT + q * 4;
    float* mop = mo + (long long)r * DFEAT + q * 4;
    atomicAdd(mip + 0, a * xr.x); atomicAdd(mip + 1, a * xr.y);
    atomicAdd(mip + 2, a * xr.z); atomicAdd(mip + 3, a * xr.w);
    atomicAdd(mop + 0, a * xc.x); atomicAdd(mop + 1, a * xc.y);
    atomicAdd(mop + 2, a * xc.z); atomicAdd(mop + 3, a * xc.w);
}

// ---- fused MLP (unchanged; next round's target) ----
__global__ __launch_bounds__(256) void mlp_kernel(
    const float* __restrict__ mi, const float* __restrict__ mo,
    const float* __restrict__ x,
    const float* __restrict__ W1, const float* __restrict__ b1,
    const float* __restrict__ W2, const float* __restrict__ b2,
    float* __restrict__ out, int N, int ngroups)
{
    __shared__ float sW1[96 * 64];
    __shared__ float sW2[64 * 64];
    __shared__ float sM[4][96];
    __shared__ float sh[4][64];

    for (int i = threadIdx.x; i < 96 * 64; i += 256) sW1[i] = W1[i];
    for (int i = threadIdx.x; i < 64 * 64; i += 256) sW2[i] = W2[i];
    __syncthreads();

    int nl = threadIdx.x >> 6;
    int o  = threadIdx.x & 63;
    float bias1 = b1[o];
    float bias2 = b2[o];

    for (int g = blockIdx.x; g < ngroups; g += gridDim.x) {
        int node0 = g * 4;
        for (int i = threadIdx.x; i < 4 * 96; i += 256) {
            int n_local = i / 96;
            int kk = i - n_local * 96;
            int node = node0 + n_local;
            float v = 0.0f;
            if (node < N) {
                if (kk < 32)      v = mi[(long long)node * 32 + kk];
                else if (kk < 64) v = mo[(long long)node * 32 + (kk - 32)];
                else              v = x [(long long)node * 32 + (kk - 64)];
            }
            sM[n_local][kk] = v;
        }
        __syncthreads();

        float acc1 = bias1;
        #pragma unroll
        for (int kk = 0; kk < 96; ++kk)
            acc1 = fmaf(sM[nl][kk], sW1[kk * 64 + o], acc1);
        sh[nl][o] = tanhf(acc1);
        __syncthreads();

        float acc2 = bias2;
        #pragma unroll
        for (int kk = 0; kk < 64; ++kk)
            acc2 = fmaf(sh[nl][kk], sW2[kk * 64 + o], acc2);

        int node = node0 + nl;
        if (node < N)
            out[(long long)node * 64 + o] = tanhf(acc2);
        __syncthreads();
    }
}

extern "C" void kernel_launch(void* const* d_in, const int* in_sizes, int n_in,
                              void* d_out, int out_size, void* d_ws, size_t ws_size,
                              hipStream_t stream) {
    const float* x  = (const float*)d_in[0];
    const int*   ei = (const int*)  d_in[1];
    const float* ea = (const float*)d_in[2];
    const float* W1 = (const float*)d_in[3];
    const float* b1 = (const float*)d_in[4];
    const float* W2 = (const float*)d_in[5];
    const float* b2 = (const float*)d_in[6];
    float* out = (float*)d_out;

    int N  = in_sizes[0] / DFEAT;    // 100000
    int E  = in_sizes[2];            // 1600000
    int NK = 2 * N;                  // keys
    int NB = (NK + KPB - 1) / KPB;   // 3125 buckets

    float* mi = (float*)d_ws;
    float* mo = mi + (size_t)N * DFEAT;

    size_t need = (size_t)N * DFEAT * 2 * 4     // mi, mo
                + (size_t)2 * E * 8             // payload
                + (size_t)NB * 3 * 4 + 4096;    // bcnt, boff, bcur, bsum
    if (ws_size >= need) {
        int2* pay = (int2*)(mo + (size_t)N * DFEAT);   // 8B-aligned
        int* bcnt = (int*)(pay + (size_t)2 * E);
        int* boff = bcnt + NB;
        int* bcur = boff + NB;
        int* bsum = bcur + NB;

        hipMemsetAsync(bcnt, 0, (size_t)NB * sizeof(int), stream);

        int eblk = (E + 255) / 256;
        hist_kernel<<<eblk, 256, 0, stream>>>(ei, bcnt, E);

        int nb = (NB + 255) / 256;               // 13
        scan_reduce<<<nb, 256, 0, stream>>>(bcnt, bsum, NB);
        scan_bsums<<<1, 1024, 0, stream>>>(bsum, nb);
        scan_final<<<nb, 256, 0, stream>>>(bcnt, bsum, boff, bcur, NB);

        scatter_kernel<<<eblk, 256, 0, stream>>>(ei, ea, bcur, pay, E);

        bucket_accum<<<NB, 256, 0, stream>>>(x, boff, bcnt, pay, mi, mo, NK);
    } else {
        hipMemsetAsync(d_ws, 0, (size_t)N * DFEAT * 2 * sizeof(float), stream);
        long long total = (long long)E * 8;
        int nblocks = (int)((total + 255) / 256);
        edge_scatter_kernel<<<nblocks, 256, 0, stream>>>(x, ei, ea, mi, mo, E);
    }

    int ngroups = (N + 3) / 4;
    int mlpblocks = ngroups < 2048 ? ngroups : 2048;
    mlp_kernel<<<mlpblocks, 256, 0, stream>>>(mi, mo, x, W1, b1, W2, b2, out, N, ngroups);
}

// Round 4
// 1156.519 us; speedup vs baseline: 1.0715x; 1.0715x over previous
//
#include <hip/hip_runtime.h>
#include <hip/hip_bf16.h>

// NodeNetwork: mi = segsum(ea*x[row] -> col), mo = segsum(ea*x[col] -> row)
// out = tanh(tanh([mi|mo|x] @ W1 + b1) @ W2 + b2)
// N=100000, D=32, O=64, E=1600000
//
// R4: counting sort with DECOUPLED granularities:
//  - hist/tickets on 8-key cursor-buckets (25000 bins, ~128-way contention;
//    R3's 3125-bin hist at 1024-way contention was ~300+ us)
//  - accumulation on 64-key groups (3125 blocks, 8KB LDS) with 8x unrolled
//    independent load chains (R3 accum was latency-bound: 1 dependent
//    pay->x chain per half-wave -> 570 us at 4.5% VALU, 4% HBM)

#define DFEAT 32
#define OFEAT 64
#define KPC   8       // keys per cursor-bucket (hist/scatter granularity)
#define KPA   64      // keys per accum group  (LDS granularity)

// ---- 1. histogram on cursor-buckets ----
__global__ __launch_bounds__(256) void hist_kernel(
    const int* __restrict__ ei, int* __restrict__ bcnt, int E)
{
    int e = blockIdx.x * 256 + threadIdx.x;
    if (e >= E) return;
    int r = ei[e];
    int c = ei[E + e];
    atomicAdd(&bcnt[(2 * c) >> 3], 1);        // key 2c     (mi)
    atomicAdd(&bcnt[(2 * r + 1) >> 3], 1);    // key 2r+1   (mo)
}

// ---- 2a. per-block reduce ----
__global__ __launch_bounds__(256) void scan_reduce(
    const int* __restrict__ cnt, int* __restrict__ bsum, int M)
{
    __shared__ int s[256];
    int i = blockIdx.x * 256 + threadIdx.x;
    s[threadIdx.x] = (i < M) ? cnt[i] : 0;
    __syncthreads();
    for (int st = 128; st > 0; st >>= 1) {
        if (threadIdx.x < st) s[threadIdx.x] += s[threadIdx.x + st];
        __syncthreads();
    }
    if (threadIdx.x == 0) bsum[blockIdx.x] = s[0];
}

// ---- 2b. single-block exclusive scan of block sums (nb <= 1024) ----
__global__ __launch_bounds__(1024) void scan_bsums(int* __restrict__ bsum, int nb)
{
    __shared__ int s[1024];
    int t = threadIdx.x;
    s[t] = (t < nb) ? bsum[t] : 0;
    __syncthreads();
    for (int off = 1; off < 1024; off <<= 1) {
        int v = (t >= off) ? s[t - off] : 0;
        __syncthreads();
        s[t] += v;
        __syncthreads();
    }
    if (t < nb) bsum[t] = (t == 0) ? 0 : s[t - 1];
}

// ---- 2c. per-block scan + block prefix -> off, cur ----
__global__ __launch_bounds__(256) void scan_final(
    const int* __restrict__ cnt, const int* __restrict__ bsum,
    int* __restrict__ off, int* __restrict__ cur, int M)
{
    __shared__ int s[256];
    int i = blockIdx.x * 256 + threadIdx.x;
    int v = (i < M) ? cnt[i] : 0;
    s[threadIdx.x] = v;
    __syncthreads();
    for (int o = 1; o < 256; o <<= 1) {
        int u = (threadIdx.x >= o) ? s[threadIdx.x - o] : 0;
        __syncthreads();
        s[threadIdx.x] += u;
        __syncthreads();
    }
    int excl = s[threadIdx.x] - v + bsum[blockIdx.x];
    if (i < M) { off[i] = excl; cur[i] = excl; }
}

// ---- 3. ticket scatter into cursor-bucket regions ----
// record: low32 = src | (lkey64 << 17), high32 = attr bits
__global__ __launch_bounds__(256) void scatter_kernel(
    const int* __restrict__ ei, const float* __restrict__ ea,
    int* __restrict__ bcur, int2* __restrict__ pay, int E)
{
    int e = blockIdx.x * 256 + threadIdx.x;
    if (e >= E) return;
    int r = ei[e];
    int c = ei[E + e];
    unsigned long long ab = (unsigned long long)(unsigned int)__float_as_int(ea[e]) << 32;

    int k0 = 2 * c;                                  // mi: src = r
    int p0 = atomicAdd(&bcur[k0 >> 3], 1);
    unsigned long long rec0 = ab | (unsigned int)(r | ((k0 & 63) << 17));
    __builtin_nontemporal_store(rec0, (unsigned long long*)(pay + p0));

    int k1 = 2 * r + 1;                              // mo: src = c
    int p1 = atomicAdd(&bcur[k1 >> 3], 1);
    unsigned long long rec1 = ab | (unsigned int)(c | ((k1 & 63) << 17));
    __builtin_nontemporal_store(rec1, (unsigned long long*)(pay + p1));
}

// ---- 4. accum: one block per 64-key group, 8x unrolled chains ----
__global__ __launch_bounds__(256) void bucket_accum(
    const float* __restrict__ x,
    const int* __restrict__ boff, const int* __restrict__ bcnt,
    const int2* __restrict__ pay,
    float* __restrict__ mi, float* __restrict__ mo, int NK, int NBC)
{
    __shared__ float acc[KPA * DFEAT];               // 8 KB
    int b = blockIdx.x;
    for (int i = threadIdx.x; i < KPA * DFEAT; i += 256) acc[i] = 0.0f;
    __syncthreads();

    int cb0 = b * (KPA / KPC);                       // first cursor-bucket
    int cb1 = cb0 + (KPA / KPC) - 1;                 // last (in range: NK%64==0 ok, else min)
    if (cb1 >= NBC) cb1 = NBC - 1;
    int base = boff[cb0];
    int end  = boff[cb1] + bcnt[cb1];
    int n    = end - base;

    int sub  = threadIdx.x >> 5;                     // 0..7
    int feat = threadIdx.x & 31;

    int full = n & ~63;
    for (int it = 0; it < full; it += 64) {
        int i0 = base + it + sub * 8;
        unsigned long long v[8];
        float xv[8];
        #pragma unroll
        for (int j = 0; j < 8; ++j)
            v[j] = __builtin_nontemporal_load((const unsigned long long*)(pay + i0 + j));
        #pragma unroll
        for (int j = 0; j < 8; ++j) {
            int src = (int)(v[j] & 0x1FFFFu);
            xv[j] = x[(long long)src * DFEAT + feat];
        }
        #pragma unroll
        for (int j = 0; j < 8; ++j) {
            int lkey = ((int)(v[j] >> 17)) & 63;
            float a  = __int_as_float((int)(v[j] >> 32));
            atomicAdd(&acc[lkey * DFEAT + feat], a * xv[j]);
        }
    }
    // tail (< 64 records)
    int t0 = base + full + sub * 8;
    #pragma unroll
    for (int j = 0; j < 8; ++j) {
        int i = t0 + j;
        if (i < end) {
            unsigned long long v = __builtin_nontemporal_load(
                (const unsigned long long*)(pay + i));
            int src  = (int)(v & 0x1FFFFu);
            int lkey = ((int)(v >> 17)) & 63;
            float a  = __int_as_float((int)(v >> 32));
            atomicAdd(&acc[lkey * DFEAT + feat], a * x[(long long)src * DFEAT + feat]);
        }
    }
    __syncthreads();

    int key0 = b * KPA;
    for (int i = threadIdx.x; i < KPA * DFEAT; i += 256) {
        int gk = key0 + (i >> 5);
        if (gk < NK) {
            int node = gk >> 1;
            float vv = acc[i];
            if (gk & 1) mo[(long long)node * DFEAT + (i & 31)] = vv;
            else        mi[(long long)node * DFEAT + (i & 31)] = vv;
        }
    }
}

// ---- R1 fallback: direct atomic scatter (ws too small) ----
__global__ __launch_bounds__(256) void edge_scatter_kernel(
    const float* __restrict__ x, const int* __restrict__ ei,
    const float* __restrict__ ea,
    float* __restrict__ mi, float* __restrict__ mo, int E)
{
    long long tid = (long long)blockIdx.x * blockDim.x + threadIdx.x;
    long long total = (long long)E * 8;
    if (tid >= total) return;
    int e = (int)(tid >> 3);
    int q = (int)(tid & 7);
    int r = ei[e];
    int c = ei[E + e];
    float a = ea[e];
    const float4* x4 = (const float4*)x;
    float4 xr = x4[(long long)r * 8 + q];
    float4 xc = x4[(long long)c * 8 + q];
    float* mip = mi + (long long)c * DFEAT + q * 4;
    float* mop = mo + (long long)r * DFEAT + q * 4;
    atomicAdd(mip + 0, a * xr.x); atomicAdd(mip + 1, a * xr.y);
    atomicAdd(mip + 2, a * xr.z); atomicAdd(mip + 3, a * xr.w);
    atomicAdd(mop + 0, a * xc.x); atomicAdd(mop + 1, a * xc.y);
    atomicAdd(mop + 2, a * xc.z); atomicAdd(mop + 3, a * xc.w);
}

// ---- fused MLP (unchanged) ----
__global__ __launch_bounds__(256) void mlp_kernel(
    const float* __restrict__ mi, const float* __restrict__ mo,
    const float* __restrict__ x,
    const float* __restrict__ W1, const float* __restrict__ b1,
    const float* __restrict__ W2, const float* __restrict__ b2,
    float* __restrict__ out, int N, int ngroups)
{
    __shared__ float sW1[96 * 64];
    __shared__ float sW2[64 * 64];
    __shared__ float sM[4][96];
    __shared__ float sh[4][64];

    for (int i = threadIdx.x; i < 96 * 64; i += 256) sW1[i] = W1[i];
    for (int i = threadIdx.x; i < 64 * 64; i += 256) sW2[i] = W2[i];
    __syncthreads();

    int nl = threadIdx.x >> 6;
    int o  = threadIdx.x & 63;
    float bias1 = b1[o];
    float bias2 = b2[o];

    for (int g = blockIdx.x; g < ngroups; g += gridDim.x) {
        int node0 = g * 4;
        for (int i = threadIdx.x; i < 4 * 96; i += 256) {
            int n_local = i / 96;
            int kk = i - n_local * 96;
            int node = node0 + n_local;
            float v = 0.0f;
            if (node < N) {
                if (kk < 32)      v = mi[(long long)node * 32 + kk];
                else if (kk < 64) v = mo[(long long)node * 32 + (kk - 32)];
                else              v = x [(long long)node * 32 + (kk - 64)];
            }
            sM[n_local][kk] = v;
        }
        __syncthreads();

        float acc1 = bias1;
        #pragma unroll
        for (int kk = 0; kk < 96; ++kk)
            acc1 = fmaf(sM[nl][kk], sW1[kk * 64 + o], acc1);
        sh[nl][o] = tanhf(acc1);
        __syncthreads();

        float acc2 = bias2;
        #pragma unroll
        for (int kk = 0; kk < 64; ++kk)
            acc2 = fmaf(sh[nl][kk], sW2[kk * 64 + o], acc2);

        int node = node0 + nl;
        if (node < N)
            out[(long long)node * 64 + o] = tanhf(acc2);
        __syncthreads();
    }
}

extern "C" void kernel_launch(void* const* d_in, const int* in_sizes, int n_in,
                              void* d_out, int out_size, void* d_ws, size_t ws_size,
                              hipStream_t stream) {
    const float* x  = (const float*)d_in[0];
    const int*   ei = (const int*)  d_in[1];
    const float* ea = (const float*)d_in[2];
    const float* W1 = (const float*)d_in[3];
    const float* b1 = (const float*)d_in[4];
    const float* W2 = (const float*)d_in[5];
    const float* b2 = (const float*)d_in[6];
    float* out = (float*)d_out;

    int N   = in_sizes[0] / DFEAT;       // 100000
    int E   = in_sizes[2];               // 1600000
    int NK  = 2 * N;                     // 200000 keys
    int NBC = (NK + KPC - 1) / KPC;      // 25000 cursor-buckets
    int NBA = (NK + KPA - 1) / KPA;      // 3125 accum groups

    float* mi = (float*)d_ws;
    float* mo = mi + (size_t)N * DFEAT;

    size_t need = (size_t)N * DFEAT * 2 * 4      // mi, mo
                + (size_t)2 * E * 8              // payload
                + (size_t)NBC * 3 * 4 + 4096;    // bcnt, boff, bcur, bsum
    if (ws_size >= need) {
        int2* pay = (int2*)(mo + (size_t)N * DFEAT);
        int* bcnt = (int*)(pay + (size_t)2 * E);
        int* boff = bcnt + NBC;
        int* bcur = boff + NBC;
        int* bsum = bcur + NBC;

        hipMemsetAsync(bcnt, 0, (size_t)NBC * sizeof(int), stream);

        int eblk = (E + 255) / 256;
        hist_kernel<<<eblk, 256, 0, stream>>>(ei, bcnt, E);

        int nb = (NBC + 255) / 256;               // 98 <= 1024
        scan_reduce<<<nb, 256, 0, stream>>>(bcnt, bsum, NBC);
        scan_bsums<<<1, 1024, 0, stream>>>(bsum, nb);
        scan_final<<<nb, 256, 0, stream>>>(bcnt, bsum, boff, bcur, NBC);

        scatter_kernel<<<eblk, 256, 0, stream>>>(ei, ea, bcur, pay, E);

        bucket_accum<<<NBA, 256, 0, stream>>>(x, boff, bcnt, pay, mi, mo, NK, NBC);
    } else {
        hipMemsetAsync(d_ws, 0, (size_t)N * DFEAT * 2 * sizeof(float), stream);
        long long total = (long long)E * 8;
        int nblocks = (int)((total + 255) / 256);
        edge_scatter_kernel<<<nblocks, 256, 0, stream>>>(x, ei, ea, mi, mo, E);
    }

    int ngroups = (N + 3) / 4;
    int mlpblocks = ngroups < 2048 ? ngroups : 2048;
    mlp_kernel<<<mlpblocks, 256, 0, stream>>>(mi, mo, x, W1, b1, W2, b2, out, N, ngroups);
}

// Round 5
// 858.387 us; speedup vs baseline: 1.4436x; 1.3473x over previous
//
#include <hip/hip_runtime.h>
#include <hip/hip_bf16.h>

// NodeNetwork: mi = segsum(ea*x[row] -> col), mo = segsum(ea*x[col] -> row)
// out = tanh(tanh([mi|mo|x] @ W1 + b1) @ W2 + b2)
// N=100000, D=32, O=64, E=1600000
//
// R5: LDS-binned partition (coalesced record writes; R2/R4 scatter wrote
// 198MB of random dirty 64B lines at 666 GB/s) + 256-key-bin LDS accum with
// int4 vector loads & explicit prefetch (R4's unroll was collapsed by the
// compiler to VGPR=20, serial chains -> 556us at 3.6% VALU).

#define DFEAT 32
#define OFEAT 64
#define EPB   2048            // edges per partition block -> 4096 records
#define KEYS_PER_BIN 256      // bin = key >> 8 ; lkey = key & 255
#define MAXBIN 1024

typedef unsigned long long u64;

// ---- A. per-block histogram over coarse bins ----
__global__ __launch_bounds__(256) void hist_part(
    const int* __restrict__ ei, int* __restrict__ blockhist, int E, int NBIN)
{
    __shared__ int lh[MAXBIN];
    int blk = blockIdx.x;
    for (int i = threadIdx.x; i < NBIN; i += 256) lh[i] = 0;
    __syncthreads();
    int e0 = blk * EPB;
    #pragma unroll
    for (int j = 0; j < 8; ++j) {
        int e = e0 + j * 256 + threadIdx.x;
        if (e < E) {
            int r = ei[e], c = ei[E + e];
            atomicAdd(&lh[(2 * c) >> 8], 1);
            atomicAdd(&lh[(2 * r + 1) >> 8], 1);
        }
    }
    __syncthreads();
    for (int i = threadIdx.x; i < NBIN; i += 256)
        blockhist[(long long)blk * NBIN + i] = lh[i];
}

// ---- B. column scan: per-bin prefix over blocks -> ofsT, bintotal ----
__global__ __launch_bounds__(64) void colscan(
    const int* __restrict__ blockhist, int* __restrict__ ofsT,
    int* __restrict__ bintotal, int nPB, int NBIN)
{
    int bin  = blockIdx.x;
    int lane = threadIdx.x;
    int run = 0;
    for (int b0 = 0; b0 < nPB; b0 += 64) {
        int b = b0 + lane;
        int v = (b < nPB) ? blockhist[(long long)b * NBIN + bin] : 0;
        int s = v;
        #pragma unroll
        for (int d = 1; d < 64; d <<= 1) {
            int t = __shfl_up(s, d, 64);
            if (lane >= d) s += t;
        }
        if (b < nPB) ofsT[(long long)bin * nPB + b] = s - v + run;
        run += __shfl(s, 63, 64);
    }
    if (lane == 0) bintotal[bin] = run;
}

// ---- C. exclusive scan of (even-padded) bin totals -> binbase ----
__global__ __launch_bounds__(1024) void scan_bins(
    const int* __restrict__ bintotal, int* __restrict__ binbase, int NBIN)
{
    __shared__ int s[1024];
    int t = threadIdx.x;
    int v = (t < NBIN) ? ((bintotal[t] + 1) & ~1) : 0;   // pad to even -> 16B align
    s[t] = v;
    __syncthreads();
    for (int o = 1; o < 1024; o <<= 1) {
        int u = (t >= o) ? s[t - o] : 0;
        __syncthreads();
        s[t] += u;
        __syncthreads();
    }
    if (t < NBIN) binbase[t] = s[t] - v;
}

// ---- D. partition: LDS reorder + coalesced flush ----
__global__ __launch_bounds__(256) void partition_kernel(
    const int* __restrict__ ei, const float* __restrict__ ea,
    const int* __restrict__ ofsT, const int* __restrict__ binbase,
    u64* __restrict__ pay, int E, int NBIN, int nPB)
{
    __shared__ int lofs[MAXBIN + 1];
    __shared__ int lcur[MAXBIN];
    __shared__ int lbase[MAXBIN];
    __shared__ u64 stag[2 * EPB];        // 32 KB
    int blk = blockIdx.x, tid = threadIdx.x;
    int e0 = blk * EPB;

    for (int i = tid; i < NBIN; i += 256) lcur[i] = 0;
    __syncthreads();

    // pass 1: load edges (kept in regs), LDS histogram
    int r[8], c[8]; float a[8]; bool valid[8];
    #pragma unroll
    for (int j = 0; j < 8; ++j) {
        int e = e0 + j * 256 + tid;
        valid[j] = (e < E);
        if (valid[j]) {
            r[j] = ei[e]; c[j] = ei[E + e]; a[j] = ea[e];
            atomicAdd(&lcur[(2 * c[j]) >> 8], 1);
            atomicAdd(&lcur[(2 * r[j] + 1) >> 8], 1);
        }
    }
    __syncthreads();

    // wave 0: exclusive scan lcur -> lofs
    if (tid < 64) {
        int runc = 0;
        for (int b0 = 0; b0 < NBIN; b0 += 64) {
            int i = b0 + tid;
            int v = (i < NBIN) ? lcur[i] : 0;
            int s = v;
            #pragma unroll
            for (int d = 1; d < 64; d <<= 1) {
                int t2 = __shfl_up(s, d, 64);
                if (tid >= d) s += t2;
            }
            if (i < NBIN) lofs[i] = s - v + runc;
            runc += __shfl(s, 63, 64);
        }
        if (tid == 0) lofs[NBIN] = runc;
    }
    __syncthreads();

    // reset tickets, compute global bases for this block
    for (int i = tid; i < NBIN; i += 256) {
        lcur[i] = 0;
        lbase[i] = binbase[i] + ofsT[(long long)i * nPB + blk];
    }
    __syncthreads();

    // pass 2: place records into LDS staging (sorted by bin)
    #pragma unroll
    for (int j = 0; j < 8; ++j) {
        if (valid[j]) {
            unsigned int ab = (unsigned int)__float_as_int(a[j]);
            {
                int key = 2 * c[j]; int bin = key >> 8;      // mi: src = r
                int t2 = atomicAdd(&lcur[bin], 1);
                stag[lofs[bin] + t2] = ((u64)ab << 32) |
                    (unsigned int)(r[j] | ((key & 255) << 17));
            }
            {
                int key = 2 * r[j] + 1; int bin = key >> 8;  // mo: src = c
                int t2 = atomicAdd(&lcur[bin], 1);
                stag[lofs[bin] + t2] = ((u64)ab << 32) |
                    (unsigned int)(c[j] | ((key & 255) << 17));
            }
        }
    }
    __syncthreads();

    // flush: contiguous runs per bin -> mostly full-line global writes
    int total = lofs[NBIN];
    for (int i = tid; i < total; i += 256) {
        int lo = 0, hi = NBIN;               // lofs[lo] <= i < lofs[hi]
        while (hi - lo > 1) {
            int mid = (lo + hi) >> 1;
            if (lofs[mid] <= i) lo = mid; else hi = mid;
        }
        pay[lbase[lo] + (i - lofs[lo])] = stag[i];
    }
}

// ---- E. accum: one block per 256-key bin, int4 loads + prefetch ----
__global__ __launch_bounds__(256) void accum256(
    const float* __restrict__ x,
    const int* __restrict__ binbase, const int* __restrict__ bintotal,
    const u64* __restrict__ pay,
    float* __restrict__ mi, float* __restrict__ mo, int NK)
{
    __shared__ float acc[KEYS_PER_BIN * DFEAT];     // 32 KB
    int b = blockIdx.x;
    for (int i = threadIdx.x; i < KEYS_PER_BIN * DFEAT; i += 256) acc[i] = 0.0f;
    __syncthreads();

    int base = binbase[b];
    int n    = bintotal[b];
    int sub  = threadIdx.x >> 5;      // 0..7
    int feat = threadIdx.x & 31;
    const u64* P = pay + base;        // 16B-aligned (base even)
    int i0 = sub * 4;

    #define PROC2(q)                                                          \
        {                                                                     \
            float xv0 = x[(long long)((q).x & 0x1FFFF) * DFEAT + feat];       \
            float xv1 = x[(long long)((q).z & 0x1FFFF) * DFEAT + feat];       \
            atomicAdd(&acc[((((q).x >> 17) & 255) << 5) + feat],              \
                      __int_as_float((q).y) * xv0);                           \
            atomicAdd(&acc[((((q).z >> 17) & 255) << 5) + feat],              \
                      __int_as_float((q).w) * xv1);                           \
        }

    int it = 0;
    int4 q0 = make_int4(0,0,0,0), q1 = q0;
    if (32 <= n) {
        q0 = *(const int4*)(P + i0);
        q1 = *(const int4*)(P + i0 + 2);
    }
    while (it + 32 <= n) {
        int nit = it + 32;
        int4 p0 = q0, p1 = q1;
        if (nit + 32 <= n) {                       // prefetch next chunk
            p0 = *(const int4*)(P + nit + i0);
            p1 = *(const int4*)(P + nit + i0 + 2);
        }
        PROC2(q0);
        PROC2(q1);
        q0 = p0; q1 = p1;
        it = nit;
    }
    // tail < 32 records
    #pragma unroll
    for (int k = 0; k < 4; ++k) {
        int idx = it + sub * 4 + k;
        if (idx < n) {
            u64 v = P[idx];
            int lw = (int)v;
            float xv = x[(long long)(lw & 0x1FFFF) * DFEAT + feat];
            atomicAdd(&acc[(((lw >> 17) & 255) << 5) + feat],
                      __int_as_float((int)(v >> 32)) * xv);
        }
    }
    #undef PROC2
    __syncthreads();

    int key0 = b * KEYS_PER_BIN;
    for (int i = threadIdx.x; i < KEYS_PER_BIN * DFEAT; i += 256) {
        int gk = key0 + (i >> 5);
        if (gk < NK) {
            int node = gk >> 1;
            float v = acc[i];
            if (gk & 1) mo[(long long)node * DFEAT + (i & 31)] = v;
            else        mi[(long long)node * DFEAT + (i & 31)] = v;
        }
    }
}

// ---- fallback: direct atomic scatter (ws too small / N too big) ----
__global__ __launch_bounds__(256) void edge_scatter_kernel(
    const float* __restrict__ x, const int* __restrict__ ei,
    const float* __restrict__ ea,
    float* __restrict__ mi, float* __restrict__ mo, int E)
{
    long long tid = (long long)blockIdx.x * blockDim.x + threadIdx.x;
    long long total = (long long)E * 8;
    if (tid >= total) return;
    int e = (int)(tid >> 3);
    int q = (int)(tid & 7);
    int r = ei[e];
    int c = ei[E + e];
    float a = ea[e];
    const float4* x4 = (const float4*)x;
    float4 xr = x4[(long long)r * 8 + q];
    float4 xc = x4[(long long)c * 8 + q];
    float* mip = mi + (long long)c * DFEAT + q * 4;
    float* mop = mo + (long long)r * DFEAT + q * 4;
    atomicAdd(mip + 0, a * xr.x); atomicAdd(mip + 1, a * xr.y);
    atomicAdd(mip + 2, a * xr.z); atomicAdd(mip + 3, a * xr.w);
    atomicAdd(mop + 0, a * xc.x); atomicAdd(mop + 1, a * xc.y);
    atomicAdd(mop + 2, a * xc.z); atomicAdd(mop + 3, a * xc.w);
}

// ---- fused MLP (unchanged) ----
__global__ __launch_bounds__(256) void mlp_kernel(
    const float* __restrict__ mi, const float* __restrict__ mo,
    const float* __restrict__ x,
    const float* __restrict__ W1, const float* __restrict__ b1,
    const float* __restrict__ W2, const float* __restrict__ b2,
    float* __restrict__ out, int N, int ngroups)
{
    __shared__ float sW1[96 * 64];
    __shared__ float sW2[64 * 64];
    __shared__ float sM[4][96];
    __shared__ float sh[4][64];

    for (int i = threadIdx.x; i < 96 * 64; i += 256) sW1[i] = W1[i];
    for (int i = threadIdx.x; i < 64 * 64; i += 256) sW2[i] = W2[i];
    __syncthreads();

    int nl = threadIdx.x >> 6;
    int o  = threadIdx.x & 63;
    float bias1 = b1[o];
    float bias2 = b2[o];

    for (int g = blockIdx.x; g < ngroups; g += gridDim.x) {
        int node0 = g * 4;
        for (int i = threadIdx.x; i < 4 * 96; i += 256) {
            int n_local = i / 96;
            int kk = i - n_local * 96;
            int node = node0 + n_local;
            float v = 0.0f;
            if (node < N) {
                if (kk < 32)      v = mi[(long long)node * 32 + kk];
                else if (kk < 64) v = mo[(long long)node * 32 + (kk - 32)];
                else              v = x [(long long)node * 32 + (kk - 64)];
            }
            sM[n_local][kk] = v;
        }
        __syncthreads();

        float acc1 = bias1;
        #pragma unroll
        for (int kk = 0; kk < 96; ++kk)
            acc1 = fmaf(sM[nl][kk], sW1[kk * 64 + o], acc1);
        sh[nl][o] = tanhf(acc1);
        __syncthreads();

        float acc2 = bias2;
        #pragma unroll
        for (int kk = 0; kk < 64; ++kk)
            acc2 = fmaf(sh[nl][kk], sW2[kk * 64 + o], acc2);

        int node = node0 + nl;
        if (node < N)
            out[(long long)node * 64 + o] = tanhf(acc2);
        __syncthreads();
    }
}

extern "C" void kernel_launch(void* const* d_in, const int* in_sizes, int n_in,
                              void* d_out, int out_size, void* d_ws, size_t ws_size,
                              hipStream_t stream) {
    const float* x  = (const float*)d_in[0];
    const int*   ei = (const int*)  d_in[1];
    const float* ea = (const float*)d_in[2];
    const float* W1 = (const float*)d_in[3];
    const float* b1 = (const float*)d_in[4];
    const float* W2 = (const float*)d_in[5];
    const float* b2 = (const float*)d_in[6];
    float* out = (float*)d_out;

    int N    = in_sizes[0] / DFEAT;              // 100000
    int E    = in_sizes[2];                      // 1600000
    int NK   = 2 * N;
    int NBIN = (NK + KEYS_PER_BIN - 1) / KEYS_PER_BIN;   // 782
    int nPB  = (E + EPB - 1) / EPB;                      // 782

    float* mi = (float*)d_ws;
    float* mo = mi + (size_t)N * DFEAT;

    size_t paySlots = (size_t)2 * E + NBIN;      // + even-padding slack
    size_t need = (size_t)N * DFEAT * 2 * 4      // mi, mo
                + paySlots * 8                   // records
                + (size_t)nPB * NBIN * 4 * 2     // blockhist + ofsT
                + (size_t)NBIN * 4 * 2 + 64;     // bintotal + binbase

    if (ws_size >= need && N <= (1 << 17) && NBIN <= MAXBIN) {
        u64* pay      = (u64*)(mo + (size_t)N * DFEAT);
        int* blockhist = (int*)(pay + paySlots);
        int* ofsT      = blockhist + (size_t)nPB * NBIN;
        int* bintotal  = ofsT + (size_t)nPB * NBIN;
        int* binbase   = bintotal + NBIN;

        hist_part<<<nPB, 256, 0, stream>>>(ei, blockhist, E, NBIN);
        colscan<<<NBIN, 64, 0, stream>>>(blockhist, ofsT, bintotal, nPB, NBIN);
        scan_bins<<<1, 1024, 0, stream>>>(bintotal, binbase, NBIN);
        partition_kernel<<<nPB, 256, 0, stream>>>(ei, ea, ofsT, binbase,
                                                  pay, E, NBIN, nPB);
        accum256<<<NBIN, 256, 0, stream>>>(x, binbase, bintotal, pay, mi, mo, NK);
    } else {
        hipMemsetAsync(d_ws, 0, (size_t)N * DFEAT * 2 * sizeof(float), stream);
        long long total = (long long)E * 8;
        int nblocks = (int)((total + 255) / 256);
        edge_scatter_kernel<<<nblocks, 256, 0, stream>>>(x, ei, ea, mi, mo, E);
    }

    int ngroups = (N + 3) / 4;
    int mlpblocks = ngroups < 2048 ? ngroups : 2048;
    mlp_kernel<<<mlpblocks, 256, 0, stream>>>(mi, mo, x, W1, b1, W2, b2, out, N, ngroups);
}

// Round 6
// 799.191 us; speedup vs baseline: 1.5506x; 1.0741x over previous
//
#include <hip/hip_runtime.h>
#include <hip/hip_bf16.h>

// NodeNetwork: mi = segsum(ea*x[row] -> col), mo = segsum(ea*x[col] -> row)
// out = tanh(tanh([mi|mo|x] @ W1 + b1) @ W2 + b2)
// N=100000, D=32, O=64, E=1600000
//
// R6: accum concurrency fix. R5's accum256 ran at 20% occupancy (782 blocks
// x 32KB LDS = 3 blocks/CU) -> latency-bound random x-gather (VALU 3%, HBM
// 3.4%). Now 2 accum blocks per 256-key bin (key-half filter), 16KB LDS,
// 1564 blocks = fully co-resident (~24 waves/CU). Partition unchanged
// (records coalesced; sort pipeline ~45us total).

#define DFEAT 32
#define OFEAT 64
#define EPB   2048            // edges per partition block -> 4096 records
#define KEYS_PER_BIN 256      // partition bin = key >> 8
#define MAXBIN 1024

typedef unsigned long long u64;
typedef int v4i __attribute__((ext_vector_type(4)));

// ---- A. per-block histogram over coarse bins ----
__global__ __launch_bounds__(256) void hist_part(
    const int* __restrict__ ei, int* __restrict__ blockhist, int E, int NBIN)
{
    __shared__ int lh[MAXBIN];
    int blk = blockIdx.x;
    for (int i = threadIdx.x; i < NBIN; i += 256) lh[i] = 0;
    __syncthreads();
    int e0 = blk * EPB;
    #pragma unroll
    for (int j = 0; j < 8; ++j) {
        int e = e0 + j * 256 + threadIdx.x;
        if (e < E) {
            int r = ei[e], c = ei[E + e];
            atomicAdd(&lh[(2 * c) >> 8], 1);
            atomicAdd(&lh[(2 * r + 1) >> 8], 1);
        }
    }
    __syncthreads();
    for (int i = threadIdx.x; i < NBIN; i += 256)
        blockhist[(long long)blk * NBIN + i] = lh[i];
}

// ---- B. column scan: per-bin prefix over blocks -> ofsT, bintotal ----
__global__ __launch_bounds__(64) void colscan(
    const int* __restrict__ blockhist, int* __restrict__ ofsT,
    int* __restrict__ bintotal, int nPB, int NBIN)
{
    int bin  = blockIdx.x;
    int lane = threadIdx.x;
    int run = 0;
    for (int b0 = 0; b0 < nPB; b0 += 64) {
        int b = b0 + lane;
        int v = (b < nPB) ? blockhist[(long long)b * NBIN + bin] : 0;
        int s = v;
        #pragma unroll
        for (int d = 1; d < 64; d <<= 1) {
            int t = __shfl_up(s, d, 64);
            if (lane >= d) s += t;
        }
        if (b < nPB) ofsT[(long long)bin * nPB + b] = s - v + run;
        run += __shfl(s, 63, 64);
    }
    if (lane == 0) bintotal[bin] = run;
}

// ---- C. exclusive scan of (even-padded) bin totals -> binbase ----
__global__ __launch_bounds__(1024) void scan_bins(
    const int* __restrict__ bintotal, int* __restrict__ binbase, int NBIN)
{
    __shared__ int s[1024];
    int t = threadIdx.x;
    int v = (t < NBIN) ? ((bintotal[t] + 1) & ~1) : 0;   // pad to even -> 16B align
    s[t] = v;
    __syncthreads();
    for (int o = 1; o < 1024; o <<= 1) {
        int u = (t >= o) ? s[t - o] : 0;
        __syncthreads();
        s[t] += u;
        __syncthreads();
    }
    if (t < NBIN) binbase[t] = s[t] - v;
}

// ---- D. partition: LDS reorder + coalesced flush ----
__global__ __launch_bounds__(256) void partition_kernel(
    const int* __restrict__ ei, const float* __restrict__ ea,
    const int* __restrict__ ofsT, const int* __restrict__ binbase,
    u64* __restrict__ pay, int E, int NBIN, int nPB)
{
    __shared__ int lofs[MAXBIN + 1];
    __shared__ int lcur[MAXBIN];
    __shared__ int lbase[MAXBIN];
    __shared__ u64 stag[2 * EPB];        // 32 KB
    int blk = blockIdx.x, tid = threadIdx.x;
    int e0 = blk * EPB;

    for (int i = tid; i < NBIN; i += 256) lcur[i] = 0;
    __syncthreads();

    // pass 1: load edges (kept in regs), LDS histogram
    int r[8], c[8]; float a[8]; bool valid[8];
    #pragma unroll
    for (int j = 0; j < 8; ++j) {
        int e = e0 + j * 256 + tid;
        valid[j] = (e < E);
        if (valid[j]) {
            r[j] = ei[e]; c[j] = ei[E + e]; a[j] = ea[e];
            atomicAdd(&lcur[(2 * c[j]) >> 8], 1);
            atomicAdd(&lcur[(2 * r[j] + 1) >> 8], 1);
        }
    }
    __syncthreads();

    // wave 0: exclusive scan lcur -> lofs
    if (tid < 64) {
        int runc = 0;
        for (int b0 = 0; b0 < NBIN; b0 += 64) {
            int i = b0 + tid;
            int v = (i < NBIN) ? lcur[i] : 0;
            int s = v;
            #pragma unroll
            for (int d = 1; d < 64; d <<= 1) {
                int t2 = __shfl_up(s, d, 64);
                if (tid >= d) s += t2;
            }
            if (i < NBIN) lofs[i] = s - v + runc;
            runc += __shfl(s, 63, 64);
        }
        if (tid == 0) lofs[NBIN] = runc;
    }
    __syncthreads();

    // reset tickets, compute global bases for this block
    for (int i = tid; i < NBIN; i += 256) {
        lcur[i] = 0;
        lbase[i] = binbase[i] + ofsT[(long long)i * nPB + blk];
    }
    __syncthreads();

    // pass 2: place records into LDS staging (sorted by bin)
    #pragma unroll
    for (int j = 0; j < 8; ++j) {
        if (valid[j]) {
            unsigned int ab = (unsigned int)__float_as_int(a[j]);
            {
                int key = 2 * c[j]; int bin = key >> 8;      // mi: src = r
                int t2 = atomicAdd(&lcur[bin], 1);
                stag[lofs[bin] + t2] = ((u64)ab << 32) |
                    (unsigned int)(r[j] | ((key & 255) << 17));
            }
            {
                int key = 2 * r[j] + 1; int bin = key >> 8;  // mo: src = c
                int t2 = atomicAdd(&lcur[bin], 1);
                stag[lofs[bin] + t2] = ((u64)ab << 32) |
                    (unsigned int)(c[j] | ((key & 255) << 17));
            }
        }
    }
    __syncthreads();

    // flush: contiguous runs per bin -> mostly full-line global writes
    int total = lofs[NBIN];
    for (int i = tid; i < total; i += 256) {
        int lo = 0, hi = NBIN;               // lofs[lo] <= i < lofs[hi]
        while (hi - lo > 1) {
            int mid = (lo + hi) >> 1;
            if (lofs[mid] <= i) lo = mid; else hi = mid;
        }
        pay[lbase[lo] + (i - lofs[lo])] = stag[i];
    }
}

// ---- E. accum: 2 blocks per 256-key bin (key-half filter), 16 KB LDS ----
__global__ __launch_bounds__(256) void accum128(
    const float* __restrict__ x,
    const int* __restrict__ binbase, const int* __restrict__ bintotal,
    const u64* __restrict__ pay,
    float* __restrict__ mi, float* __restrict__ mo, int NK)
{
    __shared__ float acc[128 * DFEAT];     // 16 KB
    int b = blockIdx.x >> 1;               // bin
    int s = blockIdx.x & 1;                // key-half
    for (int i = threadIdx.x; i < 128 * DFEAT; i += 256) acc[i] = 0.0f;
    __syncthreads();

    int base = binbase[b];
    int n    = bintotal[b];
    int sub  = threadIdx.x >> 5;      // 0..7
    int feat = threadIdx.x & 31;
    const v4i* P = (const v4i*)(pay + base);    // 16B-aligned (base even)

    // each record is broadcast to all 32 lanes of a half-wave; the key-half
    // branch is half-wave-uniform.
    #define PROC2(q)                                                         \
        {                                                                    \
            int lk0 = ((q).x >> 17) & 255;                                   \
            int lk1 = ((q).z >> 17) & 255;                                   \
            if ((lk0 >> 7) == s) {                                           \
                float xv = x[(long long)((q).x & 0x1FFFF) * DFEAT + feat];   \
                atomicAdd(&acc[((lk0 & 127) << 5) + feat],                   \
                          __int_as_float((q).y) * xv);                       \
            }                                                                \
            if ((lk1 >> 7) == s) {                                           \
                float xv = x[(long long)((q).z & 0x1FFFF) * DFEAT + feat];   \
                atomicAdd(&acc[((lk1 & 127) << 5) + feat],                   \
                          __int_as_float((q).w) * xv);                       \
            }                                                                \
        }

    int it = 0;
    v4i q0 = {0, 0, 0, 0}, q1 = q0;
    if (32 <= n) {
        q0 = __builtin_nontemporal_load(P + sub * 2);
        q1 = __builtin_nontemporal_load(P + sub * 2 + 1);
    }
    while (it + 32 <= n) {
        int nit = it + 32;
        v4i p0 = q0, p1 = q1;
        if (nit + 32 <= n) {                        // prefetch next chunk
            p0 = __builtin_nontemporal_load(P + (nit >> 1) + sub * 2);
            p1 = __builtin_nontemporal_load(P + (nit >> 1) + sub * 2 + 1);
        }
        PROC2(q0);
        PROC2(q1);
        q0 = p0; q1 = p1;
        it = nit;
    }
    // tail < 32 records
    #pragma unroll
    for (int k = 0; k < 4; ++k) {
        int idx = it + sub * 4 + k;
        if (idx < n) {
            u64 v = ((const u64*)P)[idx];
            int lw = (int)v;
            int lk = (lw >> 17) & 255;
            if ((lk >> 7) == s) {
                float xv = x[(long long)(lw & 0x1FFFF) * DFEAT + feat];
                atomicAdd(&acc[((lk & 127) << 5) + feat],
                          __int_as_float((int)(v >> 32)) * xv);
            }
        }
    }
    #undef PROC2
    __syncthreads();

    int key0 = b * KEYS_PER_BIN + s * 128;
    for (int i = threadIdx.x; i < 128 * DFEAT; i += 256) {
        int gk = key0 + (i >> 5);
        if (gk < NK) {
            int node = gk >> 1;
            float v = acc[i];
            if (gk & 1) mo[(long long)node * DFEAT + (i & 31)] = v;
            else        mi[(long long)node * DFEAT + (i & 31)] = v;
        }
    }
}

// ---- fallback: direct atomic scatter (ws too small / N too big) ----
__global__ __launch_bounds__(256) void edge_scatter_kernel(
    const float* __restrict__ x, const int* __restrict__ ei,
    const float* __restrict__ ea,
    float* __restrict__ mi, float* __restrict__ mo, int E)
{
    long long tid = (long long)blockIdx.x * blockDim.x + threadIdx.x;
    long long total = (long long)E * 8;
    if (tid >= total) return;
    int e = (int)(tid >> 3);
    int q = (int)(tid & 7);
    int r = ei[e];
    int c = ei[E + e];
    float a = ea[e];
    const float4* x4 = (const float4*)x;
    float4 xr = x4[(long long)r * 8 + q];
    float4 xc = x4[(long long)c * 8 + q];
    float* mip = mi + (long long)c * DFEAT + q * 4;
    float* mop = mo + (long long)r * DFEAT + q * 4;
    atomicAdd(mip + 0, a * xr.x); atomicAdd(mip + 1, a * xr.y);
    atomicAdd(mip + 2, a * xr.z); atomicAdd(mip + 3, a * xr.w);
    atomicAdd(mop + 0, a * xc.x); atomicAdd(mop + 1, a * xc.y);
    atomicAdd(mop + 2, a * xc.z); atomicAdd(mop + 3, a * xc.w);
}

// ---- fused MLP (unchanged) ----
__global__ __launch_bounds__(256) void mlp_kernel(
    const float* __restrict__ mi, const float* __restrict__ mo,
    const float* __restrict__ x,
    const float* __restrict__ W1, const float* __restrict__ b1,
    const float* __restrict__ W2, const float* __restrict__ b2,
    float* __restrict__ out, int N, int ngroups)
{
    __shared__ float sW1[96 * 64];
    __shared__ float sW2[64 * 64];
    __shared__ float sM[4][96];
    __shared__ float sh[4][64];

    for (int i = threadIdx.x; i < 96 * 64; i += 256) sW1[i] = W1[i];
    for (int i = threadIdx.x; i < 64 * 64; i += 256) sW2[i] = W2[i];
    __syncthreads();

    int nl = threadIdx.x >> 6;
    int o  = threadIdx.x & 63;
    float bias1 = b1[o];
    float bias2 = b2[o];

    for (int g = blockIdx.x; g < ngroups; g += gridDim.x) {
        int node0 = g * 4;
        for (int i = threadIdx.x; i < 4 * 96; i += 256) {
            int n_local = i / 96;
            int kk = i - n_local * 96;
            int node = node0 + n_local;
            float v = 0.0f;
            if (node < N) {
                if (kk < 32)      v = mi[(long long)node * 32 + kk];
                else if (kk < 64) v = mo[(long long)node * 32 + (kk - 32)];
                else              v = x [(long long)node * 32 + (kk - 64)];
            }
            sM[n_local][kk] = v;
        }
        __syncthreads();

        float acc1 = bias1;
        #pragma unroll
        for (int kk = 0; kk < 96; ++kk)
            acc1 = fmaf(sM[nl][kk], sW1[kk * 64 + o], acc1);
        sh[nl][o] = tanhf(acc1);
        __syncthreads();

        float acc2 = bias2;
        #pragma unroll
        for (int kk = 0; kk < 64; ++kk)
            acc2 = fmaf(sh[nl][kk], sW2[kk * 64 + o], acc2);

        int node = node0 + nl;
        if (node < N)
            out[(long long)node * 64 + o] = tanhf(acc2);
        __syncthreads();
    }
}

extern "C" void kernel_launch(void* const* d_in, const int* in_sizes, int n_in,
                              void* d_out, int out_size, void* d_ws, size_t ws_size,
                              hipStream_t stream) {
    const float* x  = (const float*)d_in[0];
    const int*   ei = (const int*)  d_in[1];
    const float* ea = (const float*)d_in[2];
    const float* W1 = (const float*)d_in[3];
    const float* b1 = (const float*)d_in[4];
    const float* W2 = (const float*)d_in[5];
    const float* b2 = (const float*)d_in[6];
    float* out = (float*)d_out;

    int N    = in_sizes[0] / DFEAT;              // 100000
    int E    = in_sizes[2];                      // 1600000
    int NK   = 2 * N;
    int NBIN = (NK + KEYS_PER_BIN - 1) / KEYS_PER_BIN;   // 782
    int nPB  = (E + EPB - 1) / EPB;                      // 782

    float* mi = (float*)d_ws;
    float* mo = mi + (size_t)N * DFEAT;

    size_t paySlots = (size_t)2 * E + NBIN;      // + even-padding slack
    size_t need = (size_t)N * DFEAT * 2 * 4      // mi, mo
                + paySlots * 8                   // records
                + (size_t)nPB * NBIN * 4 * 2     // blockhist + ofsT
                + (size_t)NBIN * 4 * 2 + 64;     // bintotal + binbase

    if (ws_size >= need && N <= (1 << 17) && NBIN <= MAXBIN) {
        u64* pay       = (u64*)(mo + (size_t)N * DFEAT);
        int* blockhist = (int*)(pay + paySlots);
        int* ofsT      = blockhist + (size_t)nPB * NBIN;
        int* bintotal  = ofsT + (size_t)nPB * NBIN;
        int* binbase   = bintotal + NBIN;

        hist_part<<<nPB, 256, 0, stream>>>(ei, blockhist, E, NBIN);
        colscan<<<NBIN, 64, 0, stream>>>(blockhist, ofsT, bintotal, nPB, NBIN);
        scan_bins<<<1, 1024, 0, stream>>>(bintotal, binbase, NBIN);
        partition_kernel<<<nPB, 256, 0, stream>>>(ei, ea, ofsT, binbase,
                                                  pay, E, NBIN, nPB);
        accum128<<<NBIN * 2, 256, 0, stream>>>(x, binbase, bintotal, pay,
                                               mi, mo, NK);
    } else {
        hipMemsetAsync(d_ws, 0, (size_t)N * DFEAT * 2 * sizeof(float), stream);
        long long total = (long long)E * 8;
        int nblocks = (int)((total + 255) / 256);
        edge_scatter_kernel<<<nblocks, 256, 0, stream>>>(x, ei, ea, mi, mo, E);
    }

    int ngroups = (N + 3) / 4;
    int mlpblocks = ngroups < 2048 ? ngroups : 2048;
    mlp_kernel<<<mlpblocks, 256, 0, stream>>>(mi, mo, x, W1, b1, W2, b2, out, N, ngroups);
}

// Round 7
// 786.150 us; speedup vs baseline: 1.5763x; 1.0166x over previous
//
#include <hip/hip_runtime.h>
#include <hip/hip_bf16.h>

// NodeNetwork: mi = segsum(ea*x[row] -> col), mo = segsum(ea*x[col] -> row)
// out = tanh(tanh([mi|mo|x] @ W1 + b1) @ W2 + b2)
// N=100000, D=32, O=64, E=1600000
//
// R7: accum restructured to PER-LANE record parallelism. R4/R5/R6 all hit
// the same wall: broadcast-one-record-per-half-wave leaves one dependent
// pay->x->atomic chain per half-wave and the compiler refuses to keep
// prefetch registers live (R6 VGPR=12). Now: thread = (record, chunk);
// 8 lanes/record read the x row coalesced; LDS ds_add accumulate; lanes'
// iterations are independent -> latency hidden by TLP, not ILP.
// Bins shrink to 128 keys -> 1563 accum blocks (R5's 782-block grid was
// only 3 blocks/CU).

#define DFEAT 32
#define OFEAT 64
#define EPB   2048            // edges per partition block -> 4096 records
#define KEYS_PER_BIN 128      // partition bin = key >> 7 ; lkey = key & 127
#define MAXBIN 2048

typedef unsigned long long u64;

// ---- A. per-block histogram over bins ----
__global__ __launch_bounds__(256) void hist_part(
    const int* __restrict__ ei, int* __restrict__ blockhist, int E, int NBIN)
{
    __shared__ int lh[MAXBIN];
    int blk = blockIdx.x;
    for (int i = threadIdx.x; i < NBIN; i += 256) lh[i] = 0;
    __syncthreads();
    int e0 = blk * EPB;
    #pragma unroll
    for (int j = 0; j < 8; ++j) {
        int e = e0 + j * 256 + threadIdx.x;
        if (e < E) {
            int r = ei[e], c = ei[E + e];
            atomicAdd(&lh[(2 * c) >> 7], 1);
            atomicAdd(&lh[(2 * r + 1) >> 7], 1);
        }
    }
    __syncthreads();
    for (int i = threadIdx.x; i < NBIN; i += 256)
        blockhist[(long long)blk * NBIN + i] = lh[i];
}

// ---- B. column scan: per-bin prefix over blocks -> ofsT, bintotal ----
__global__ __launch_bounds__(64) void colscan(
    const int* __restrict__ blockhist, int* __restrict__ ofsT,
    int* __restrict__ bintotal, int nPB, int NBIN)
{
    int bin  = blockIdx.x;
    int lane = threadIdx.x;
    int run = 0;
    for (int b0 = 0; b0 < nPB; b0 += 64) {
        int b = b0 + lane;
        int v = (b < nPB) ? blockhist[(long long)b * NBIN + bin] : 0;
        int s = v;
        #pragma unroll
        for (int d = 1; d < 64; d <<= 1) {
            int t = __shfl_up(s, d, 64);
            if (lane >= d) s += t;
        }
        if (b < nPB) ofsT[(long long)bin * nPB + b] = s - v + run;
        run += __shfl(s, 63, 64);
    }
    if (lane == 0) bintotal[bin] = run;
}

// ---- C. exclusive scan of (even-padded) bin totals, up to 2048 bins ----
__global__ __launch_bounds__(1024) void scan_bins(
    const int* __restrict__ bintotal, int* __restrict__ binbase, int NBIN)
{
    __shared__ int s[1024];
    int t = threadIdx.x;
    int i0 = 2 * t, i1 = 2 * t + 1;
    int p0 = (i0 < NBIN) ? ((bintotal[i0] + 1) & ~1) : 0;  // even-pad -> 16B align
    int p1 = (i1 < NBIN) ? ((bintotal[i1] + 1) & ~1) : 0;
    int v = p0 + p1;
    s[t] = v;
    __syncthreads();
    for (int o = 1; o < 1024; o <<= 1) {
        int u = (t >= o) ? s[t - o] : 0;
        __syncthreads();
        s[t] += u;
        __syncthreads();
    }
    int excl = s[t] - v;
    if (i0 < NBIN) binbase[i0] = excl;
    if (i1 < NBIN) binbase[i1] = excl + p0;
}

// ---- D. partition: LDS reorder + coalesced flush ----
__global__ __launch_bounds__(256) void partition_kernel(
    const int* __restrict__ ei, const float* __restrict__ ea,
    const int* __restrict__ ofsT, const int* __restrict__ binbase,
    u64* __restrict__ pay, int E, int NBIN, int nPB)
{
    __shared__ int lofs[MAXBIN + 1];
    __shared__ int lcur[MAXBIN];
    __shared__ int lbase[MAXBIN];
    __shared__ u64 stag[2 * EPB];        // 32 KB
    int blk = blockIdx.x, tid = threadIdx.x;
    int e0 = blk * EPB;

    for (int i = tid; i < NBIN; i += 256) lcur[i] = 0;
    __syncthreads();

    // pass 1: load edges (kept in regs), LDS histogram
    int r[8], c[8]; float a[8]; bool valid[8];
    #pragma unroll
    for (int j = 0; j < 8; ++j) {
        int e = e0 + j * 256 + tid;
        valid[j] = (e < E);
        if (valid[j]) {
            r[j] = ei[e]; c[j] = ei[E + e]; a[j] = ea[e];
            atomicAdd(&lcur[(2 * c[j]) >> 7], 1);
            atomicAdd(&lcur[(2 * r[j] + 1) >> 7], 1);
        }
    }
    __syncthreads();

    // wave 0: exclusive scan lcur -> lofs
    if (tid < 64) {
        int runc = 0;
        for (int b0 = 0; b0 < NBIN; b0 += 64) {
            int i = b0 + tid;
            int v = (i < NBIN) ? lcur[i] : 0;
            int s = v;
            #pragma unroll
            for (int d = 1; d < 64; d <<= 1) {
                int t2 = __shfl_up(s, d, 64);
                if (tid >= d) s += t2;
            }
            if (i < NBIN) lofs[i] = s - v + runc;
            runc += __shfl(s, 63, 64);
        }
        if (tid == 0) lofs[NBIN] = runc;
    }
    __syncthreads();

    // reset tickets, compute global bases for this block
    for (int i = tid; i < NBIN; i += 256) {
        lcur[i] = 0;
        lbase[i] = binbase[i] + ofsT[(long long)i * nPB + blk];
    }
    __syncthreads();

    // pass 2: place records into LDS staging (sorted by bin)
    #pragma unroll
    for (int j = 0; j < 8; ++j) {
        if (valid[j]) {
            unsigned int ab = (unsigned int)__float_as_int(a[j]);
            {
                int key = 2 * c[j]; int bin = key >> 7;      // mi: src = r
                int t2 = atomicAdd(&lcur[bin], 1);
                stag[lofs[bin] + t2] = ((u64)ab << 32) |
                    (unsigned int)(r[j] | ((key & 127) << 17));
            }
            {
                int key = 2 * r[j] + 1; int bin = key >> 7;  // mo: src = c
                int t2 = atomicAdd(&lcur[bin], 1);
                stag[lofs[bin] + t2] = ((u64)ab << 32) |
                    (unsigned int)(c[j] | ((key & 127) << 17));
            }
        }
    }
    __syncthreads();

    // flush: contiguous runs per bin -> mostly full-line global writes
    int total = lofs[NBIN];
    for (int i = tid; i < total; i += 256) {
        int lo = 0, hi = NBIN;               // lofs[lo] <= i < lofs[hi]
        while (hi - lo > 1) {
            int mid = (lo + hi) >> 1;
            if (lofs[mid] <= i) lo = mid; else hi = mid;
        }
        pay[lbase[lo] + (i - lofs[lo])] = stag[i];
    }
}

// ---- E. accum: 1 block per 128-key bin; thread = (record, float4 chunk) ----
__global__ __launch_bounds__(256) void accum_gather(
    const float* __restrict__ x,
    const int* __restrict__ binbase, const int* __restrict__ bintotal,
    const u64* __restrict__ pay,
    float* __restrict__ mi, float* __restrict__ mo, int NK)
{
    __shared__ float acc[KEYS_PER_BIN * DFEAT];     // 16 KB
    int b = blockIdx.x;
    for (int i = threadIdx.x; i < KEYS_PER_BIN * DFEAT; i += 256) acc[i] = 0.0f;
    __syncthreads();

    int base = binbase[b];
    int n    = bintotal[b];
    int rg   = threadIdx.x >> 3;      // 0..31: record slot within chunk of 32
    int q    = threadIdx.x & 7;       // float4 chunk of the 32-feature row
    const u64* P = pay + base;
    const float4* x4 = (const float4*)x;

    for (int it = rg; it < n; it += 32) {
        u64 v = __builtin_nontemporal_load(P + it);
        int lw   = (int)v;
        int src  = lw & 0x1FFFF;
        int lkey = (lw >> 17) & 127;
        float a  = __int_as_float((int)(v >> 32));
        float4 xv = x4[(long long)src * 8 + q];       // 8 lanes -> 128B row
        float* d = &acc[(lkey << 5) + (q << 2)];
        atomicAdd(d + 0, a * xv.x);
        atomicAdd(d + 1, a * xv.y);
        atomicAdd(d + 2, a * xv.z);
        atomicAdd(d + 3, a * xv.w);
    }
    __syncthreads();

    int key0 = b * KEYS_PER_BIN;
    for (int i = threadIdx.x; i < KEYS_PER_BIN * DFEAT; i += 256) {
        int gk = key0 + (i >> 5);
        if (gk < NK) {
            int node = gk >> 1;
            float vv = acc[i];
            if (gk & 1) mo[(long long)node * DFEAT + (i & 31)] = vv;
            else        mi[(long long)node * DFEAT + (i & 31)] = vv;
        }
    }
}

// ---- fallback: direct atomic scatter (ws too small / N too big) ----
__global__ __launch_bounds__(256) void edge_scatter_kernel(
    const float* __restrict__ x, const int* __restrict__ ei,
    const float* __restrict__ ea,
    float* __restrict__ mi, float* __restrict__ mo, int E)
{
    long long tid = (long long)blockIdx.x * blockDim.x + threadIdx.x;
    long long total = (long long)E * 8;
    if (tid >= total) return;
    int e = (int)(tid >> 3);
    int q = (int)(tid & 7);
    int r = ei[e];
    int c = ei[E + e];
    float a = ea[e];
    const float4* x4 = (const float4*)x;
    float4 xr = x4[(long long)r * 8 + q];
    float4 xc = x4[(long long)c * 8 + q];
    float* mip = mi + (long long)c * DFEAT + q * 4;
    float* mop = mo + (long long)r * DFEAT + q * 4;
    atomicAdd(mip + 0, a * xr.x); atomicAdd(mip + 1, a * xr.y);
    atomicAdd(mip + 2, a * xr.z); atomicAdd(mip + 3, a * xr.w);
    atomicAdd(mop + 0, a * xc.x); atomicAdd(mop + 1, a * xc.y);
    atomicAdd(mop + 2, a * xc.z); atomicAdd(mop + 3, a * xc.w);
}

// ---- fused MLP (unchanged) ----
__global__ __launch_bounds__(256) void mlp_kernel(
    const float* __restrict__ mi, const float* __restrict__ mo,
    const float* __restrict__ x,
    const float* __restrict__ W1, const float* __restrict__ b1,
    const float* __restrict__ W2, const float* __restrict__ b2,
    float* __restrict__ out, int N, int ngroups)
{
    __shared__ float sW1[96 * 64];
    __shared__ float sW2[64 * 64];
    __shared__ float sM[4][96];
    __shared__ float sh[4][64];

    for (int i = threadIdx.x; i < 96 * 64; i += 256) sW1[i] = W1[i];
    for (int i = threadIdx.x; i < 64 * 64; i += 256) sW2[i] = W2[i];
    __syncthreads();

    int nl = threadIdx.x >> 6;
    int o  = threadIdx.x & 63;
    float bias1 = b1[o];
    float bias2 = b2[o];

    for (int g = blockIdx.x; g < ngroups; g += gridDim.x) {
        int node0 = g * 4;
        for (int i = threadIdx.x; i < 4 * 96; i += 256) {
            int n_local = i / 96;
            int kk = i - n_local * 96;
            int node = node0 + n_local;
            float v = 0.0f;
            if (node < N) {
                if (kk < 32)      v = mi[(long long)node * 32 + kk];
                else if (kk < 64) v = mo[(long long)node * 32 + (kk - 32)];
                else              v = x [(long long)node * 32 + (kk - 64)];
            }
            sM[n_local][kk] = v;
        }
        __syncthreads();

        float acc1 = bias1;
        #pragma unroll
        for (int kk = 0; kk < 96; ++kk)
            acc1 = fmaf(sM[nl][kk], sW1[kk * 64 + o], acc1);
        sh[nl][o] = tanhf(acc1);
        __syncthreads();

        float acc2 = bias2;
        #pragma unroll
        for (int kk = 0; kk < 64; ++kk)
            acc2 = fmaf(sh[nl][kk], sW2[kk * 64 + o], acc2);

        int node = node0 + nl;
        if (node < N)
            out[(long long)node * 64 + o] = tanhf(acc2);
        __syncthreads();
    }
}

extern "C" void kernel_launch(void* const* d_in, const int* in_sizes, int n_in,
                              void* d_out, int out_size, void* d_ws, size_t ws_size,
                              hipStream_t stream) {
    const float* x  = (const float*)d_in[0];
    const int*   ei = (const int*)  d_in[1];
    const float* ea = (const float*)d_in[2];
    const float* W1 = (const float*)d_in[3];
    const float* b1 = (const float*)d_in[4];
    const float* W2 = (const float*)d_in[5];
    const float* b2 = (const float*)d_in[6];
    float* out = (float*)d_out;

    int N    = in_sizes[0] / DFEAT;              // 100000
    int E    = in_sizes[2];                      // 1600000
    int NK   = 2 * N;
    int NBIN = (NK + KEYS_PER_BIN - 1) / KEYS_PER_BIN;   // 1563
    int nPB  = (E + EPB - 1) / EPB;                      // 782

    float* mi = (float*)d_ws;
    float* mo = mi + (size_t)N * DFEAT;

    size_t paySlots = (size_t)2 * E + NBIN;      // + even-padding slack
    size_t need = (size_t)N * DFEAT * 2 * 4      // mi, mo
                + paySlots * 8                   // records
                + (size_t)nPB * NBIN * 4 * 2     // blockhist + ofsT
                + (size_t)NBIN * 4 * 2 + 64;     // bintotal + binbase

    if (ws_size >= need && N <= (1 << 17) && NBIN <= MAXBIN) {
        u64* pay       = (u64*)(mo + (size_t)N * DFEAT);
        int* blockhist = (int*)(pay + paySlots);
        int* ofsT      = blockhist + (size_t)nPB * NBIN;
        int* bintotal  = ofsT + (size_t)nPB * NBIN;
        int* binbase   = bintotal + NBIN;

        hist_part<<<nPB, 256, 0, stream>>>(ei, blockhist, E, NBIN);
        colscan<<<NBIN, 64, 0, stream>>>(blockhist, ofsT, bintotal, nPB, NBIN);
        scan_bins<<<1, 1024, 0, stream>>>(bintotal, binbase, NBIN);
        partition_kernel<<<nPB, 256, 0, stream>>>(ei, ea, ofsT, binbase,
                                                  pay, E, NBIN, nPB);
        accum_gather<<<NBIN, 256, 0, stream>>>(x, binbase, bintotal, pay,
                                               mi, mo, NK);
    } else {
        hipMemsetAsync(d_ws, 0, (size_t)N * DFEAT * 2 * sizeof(float), stream);
        long long total = (long long)E * 8;
        int nblocks = (int)((total + 255) / 256);
        edge_scatter_kernel<<<nblocks, 256, 0, stream>>>(x, ei, ea, mi, mo, E);
    }

    int ngroups = (N + 3) / 4;
    int mlpblocks = ngroups < 2048 ? ngroups : 2048;
    mlp_kernel<<<mlpblocks, 256, 0, stream>>>(mi, mo, x, W1, b1, W2, b2, out, N, ngroups);
}

// Round 8
// 323.415 us; speedup vs baseline: 3.8316x; 2.4308x over previous
//
#include <hip/hip_runtime.h>
#include <hip/hip_bf16.h>

// NodeNetwork: mi = segsum(ea*x[row] -> col), mo = segsum(ea*x[col] -> row)
// out = tanh(tanh([mi|mo|x] @ W1 + b1) @ W2 + b2)
// N=100000, D=32, O=64, E=1600000
//
// R8: partition pipeline (R5/R7, coalesced record writes) + per-key REGISTER
// gather (R2's structure, ~160us measured, vs ~600us for every per-bin LDS
// accumulation variant R5-R7). Accum block: in-LDS counting sort of the
// bin's records by key, then wave-per-32-keys dual-chain register gather:
// every vmem instruction touches 1-2 cache lines (broadcast LDS record read,
// coalesced 128B x-row), no NT loads, no ds_add in hot loop, 4 rows in
// flight per wave, ~24 waves/CU.

#define DFEAT 32
#define OFEAT 64
#define EPB   2048            // edges per partition block -> 4096 records
#define KEYS_PER_BIN 128      // partition bin = key >> 7 ; lkey = key & 127
#define MAXBIN 2048
#define CAP   3072            // records staged per chunk (24 KB)

typedef unsigned long long u64;

// ---- A. per-block histogram over bins ----
__global__ __launch_bounds__(256) void hist_part(
    const int* __restrict__ ei, int* __restrict__ blockhist, int E, int NBIN)
{
    __shared__ int lh[MAXBIN];
    int blk = blockIdx.x;
    for (int i = threadIdx.x; i < NBIN; i += 256) lh[i] = 0;
    __syncthreads();
    int e0 = blk * EPB;
    #pragma unroll
    for (int j = 0; j < 8; ++j) {
        int e = e0 + j * 256 + threadIdx.x;
        if (e < E) {
            int r = ei[e], c = ei[E + e];
            atomicAdd(&lh[(2 * c) >> 7], 1);
            atomicAdd(&lh[(2 * r + 1) >> 7], 1);
        }
    }
    __syncthreads();
    for (int i = threadIdx.x; i < NBIN; i += 256)
        blockhist[(long long)blk * NBIN + i] = lh[i];
}

// ---- B. column scan: per-bin prefix over blocks -> ofsT, bintotal ----
__global__ __launch_bounds__(64) void colscan(
    const int* __restrict__ blockhist, int* __restrict__ ofsT,
    int* __restrict__ bintotal, int nPB, int NBIN)
{
    int bin  = blockIdx.x;
    int lane = threadIdx.x;
    int run = 0;
    for (int b0 = 0; b0 < nPB; b0 += 64) {
        int b = b0 + lane;
        int v = (b < nPB) ? blockhist[(long long)b * NBIN + bin] : 0;
        int s = v;
        #pragma unroll
        for (int d = 1; d < 64; d <<= 1) {
            int t = __shfl_up(s, d, 64);
            if (lane >= d) s += t;
        }
        if (b < nPB) ofsT[(long long)bin * nPB + b] = s - v + run;
        run += __shfl(s, 63, 64);
    }
    if (lane == 0) bintotal[bin] = run;
}

// ---- C. exclusive scan of (even-padded) bin totals, up to 2048 bins ----
__global__ __launch_bounds__(1024) void scan_bins(
    const int* __restrict__ bintotal, int* __restrict__ binbase, int NBIN)
{
    __shared__ int s[1024];
    int t = threadIdx.x;
    int i0 = 2 * t, i1 = 2 * t + 1;
    int p0 = (i0 < NBIN) ? ((bintotal[i0] + 1) & ~1) : 0;  // even-pad -> 16B align
    int p1 = (i1 < NBIN) ? ((bintotal[i1] + 1) & ~1) : 0;
    int v = p0 + p1;
    s[t] = v;
    __syncthreads();
    for (int o = 1; o < 1024; o <<= 1) {
        int u = (t >= o) ? s[t - o] : 0;
        __syncthreads();
        s[t] += u;
        __syncthreads();
    }
    int excl = s[t] - v;
    if (i0 < NBIN) binbase[i0] = excl;
    if (i1 < NBIN) binbase[i1] = excl + p0;
}

// ---- D. partition: LDS reorder + coalesced flush ----
__global__ __launch_bounds__(256) void partition_kernel(
    const int* __restrict__ ei, const float* __restrict__ ea,
    const int* __restrict__ ofsT, const int* __restrict__ binbase,
    u64* __restrict__ pay, int E, int NBIN, int nPB)
{
    __shared__ int lofs[MAXBIN + 1];
    __shared__ int lcur[MAXBIN];
    __shared__ int lbase[MAXBIN];
    __shared__ u64 stag[2 * EPB];        // 32 KB
    int blk = blockIdx.x, tid = threadIdx.x;
    int e0 = blk * EPB;

    for (int i = tid; i < NBIN; i += 256) lcur[i] = 0;
    __syncthreads();

    // pass 1: load edges (kept in regs), LDS histogram
    int r[8], c[8]; float a[8]; bool valid[8];
    #pragma unroll
    for (int j = 0; j < 8; ++j) {
        int e = e0 + j * 256 + tid;
        valid[j] = (e < E);
        if (valid[j]) {
            r[j] = ei[e]; c[j] = ei[E + e]; a[j] = ea[e];
            atomicAdd(&lcur[(2 * c[j]) >> 7], 1);
            atomicAdd(&lcur[(2 * r[j] + 1) >> 7], 1);
        }
    }
    __syncthreads();

    // wave 0: exclusive scan lcur -> lofs
    if (tid < 64) {
        int runc = 0;
        for (int b0 = 0; b0 < NBIN; b0 += 64) {
            int i = b0 + tid;
            int v = (i < NBIN) ? lcur[i] : 0;
            int s = v;
            #pragma unroll
            for (int d = 1; d < 64; d <<= 1) {
                int t2 = __shfl_up(s, d, 64);
                if (tid >= d) s += t2;
            }
            if (i < NBIN) lofs[i] = s - v + runc;
            runc += __shfl(s, 63, 64);
        }
        if (tid == 0) lofs[NBIN] = runc;
    }
    __syncthreads();

    // reset tickets, compute global bases for this block
    for (int i = tid; i < NBIN; i += 256) {
        lcur[i] = 0;
        lbase[i] = binbase[i] + ofsT[(long long)i * nPB + blk];
    }
    __syncthreads();

    // pass 2: place records into LDS staging (sorted by bin)
    #pragma unroll
    for (int j = 0; j < 8; ++j) {
        if (valid[j]) {
            unsigned int ab = (unsigned int)__float_as_int(a[j]);
            {
                int key = 2 * c[j]; int bin = key >> 7;      // mi: src = r
                int t2 = atomicAdd(&lcur[bin], 1);
                stag[lofs[bin] + t2] = ((u64)ab << 32) |
                    (unsigned int)(r[j] | ((key & 127) << 17));
            }
            {
                int key = 2 * r[j] + 1; int bin = key >> 7;  // mo: src = c
                int t2 = atomicAdd(&lcur[bin], 1);
                stag[lofs[bin] + t2] = ((u64)ab << 32) |
                    (unsigned int)(c[j] | ((key & 127) << 17));
            }
        }
    }
    __syncthreads();

    // flush: contiguous runs per bin -> mostly full-line global writes
    int total = lofs[NBIN];
    for (int i = tid; i < total; i += 256) {
        int lo = 0, hi = NBIN;               // lofs[lo] <= i < lofs[hi]
        while (hi - lo > 1) {
            int mid = (lo + hi) >> 1;
            if (lofs[mid] <= i) lo = mid; else hi = mid;
        }
        pay[lbase[lo] + (i - lofs[lo])] = stag[i];
    }
}

// ---- E. accum: in-LDS key sort + per-key dual-chain register gather ----
__global__ __launch_bounds__(256) void accum_sortgather(
    const float* __restrict__ x,
    const int* __restrict__ binbase, const int* __restrict__ bintotal,
    const u64* __restrict__ pay,
    float* __restrict__ mi, float* __restrict__ mo, int NK)
{
    __shared__ u64 srec[CAP];                 // 24 KB, records sorted by key
    __shared__ int lcnt[KEYS_PER_BIN];
    __shared__ int lofs[KEYS_PER_BIN];
    __shared__ int lcur[KEYS_PER_BIN];

    int b = blockIdx.x, tid = threadIdx.x;
    int base = binbase[b];
    int n    = bintotal[b];
    int wid  = tid >> 6;        // 0..3: wave -> owns keys [wid*32, wid*32+32)
    int lane = tid & 63;
    int half = lane >> 5;       // dual record chains per half-wave
    int feat = lane & 31;

    float acc0[16], acc1[16];
    #pragma unroll
    for (int p = 0; p < 16; ++p) { acc0[p] = 0.0f; acc1[p] = 0.0f; }

    for (int c0 = 0; c0 < n; c0 += CAP) {
        int cn = min(n - c0, CAP);
        if (tid < KEYS_PER_BIN) lcnt[tid] = 0;
        __syncthreads();
        // count keys in this chunk
        for (int i = tid; i < cn; i += 256)
            atomicAdd(&lcnt[((int)pay[base + c0 + i] >> 17) & 127], 1);
        __syncthreads();
        // exclusive scan of 128 counters (wave 0, 2 keys/lane)
        if (tid < 64) {
            int v0 = lcnt[2 * tid], v1 = lcnt[2 * tid + 1];
            int s = v0 + v1, ss = s;
            #pragma unroll
            for (int d = 1; d < 64; d <<= 1) {
                int t = __shfl_up(ss, d, 64);
                if (tid >= d) ss += t;
            }
            int excl = ss - s;
            lofs[2 * tid] = excl;      lofs[2 * tid + 1] = excl + v0;
            lcur[2 * tid] = excl;      lcur[2 * tid + 1] = excl + v0;
        }
        __syncthreads();
        // place records sorted by key
        for (int i = tid; i < cn; i += 256) {
            u64 v = pay[base + c0 + i];              // L2-hot re-read
            int t2 = atomicAdd(&lcur[((int)v >> 17) & 127], 1);
            srec[t2] = v;
        }
        __syncthreads();

        // gather: 16 key-pairs per wave, two independent chains per half
        #pragma unroll
        for (int p = 0; p < 16; ++p) {
            int kA = wid * 32 + 2 * p;
            int kB = kA + 1;
            int sA = lofs[kA], eA = sA + lcnt[kA];
            int sB = lofs[kB], eB = sB + lcnt[kB];
            int iA = sA + half, iB = sB + half;
            float aA = acc0[p], aB = acc1[p];
            while (iA < eA && iB < eB) {
                u64 ra = srec[iA], rb = srec[iB];
                float xa = x[(long long)((int)ra & 0x1FFFF) * DFEAT + feat];
                float xb = x[(long long)((int)rb & 0x1FFFF) * DFEAT + feat];
                aA = fmaf(__int_as_float((int)(ra >> 32)), xa, aA);
                aB = fmaf(__int_as_float((int)(rb >> 32)), xb, aB);
                iA += 2; iB += 2;
            }
            while (iA < eA) {
                u64 ra = srec[iA];
                float xa = x[(long long)((int)ra & 0x1FFFF) * DFEAT + feat];
                aA = fmaf(__int_as_float((int)(ra >> 32)), xa, aA);
                iA += 2;
            }
            while (iB < eB) {
                u64 rb = srec[iB];
                float xb = x[(long long)((int)rb & 0x1FFFF) * DFEAT + feat];
                aB = fmaf(__int_as_float((int)(rb >> 32)), xb, aB);
                iB += 2;
            }
            acc0[p] = aA; acc1[p] = aB;
        }
        __syncthreads();    // protect srec/lcnt before next chunk
    }

    // combine halves; lanes 0-31 write key kA's row, lanes 32-63 key kB's
    int key0 = b * KEYS_PER_BIN + wid * 32;
    #pragma unroll
    for (int p = 0; p < 16; ++p) {
        float tA = acc0[p] + __shfl_xor(acc0[p], 32, 64);
        float tB = acc1[p] + __shfl_xor(acc1[p], 32, 64);
        int gk = key0 + 2 * p + half;
        float v = half ? tB : tA;
        if (gk < NK) {
            int node = gk >> 1;
            float* dst = (gk & 1) ? mo : mi;
            dst[(long long)node * DFEAT + feat] = v;
        }
    }
}

// ---- fallback: direct atomic scatter (ws too small / N too big) ----
__global__ __launch_bounds__(256) void edge_scatter_kernel(
    const float* __restrict__ x, const int* __restrict__ ei,
    const float* __restrict__ ea,
    float* __restrict__ mi, float* __restrict__ mo, int E)
{
    long long tid = (long long)blockIdx.x * blockDim.x + threadIdx.x;
    long long total = (long long)E * 8;
    if (tid >= total) return;
    int e = (int)(tid >> 3);
    int q = (int)(tid & 7);
    int r = ei[e];
    int c = ei[E + e];
    float a = ea[e];
    const float4* x4 = (const float4*)x;
    float4 xr = x4[(long long)r * 8 + q];
    float4 xc = x4[(long long)c * 8 + q];
    float* mip = mi + (long long)c * DFEAT + q * 4;
    float* mop = mo + (long long)r * DFEAT + q * 4;
    atomicAdd(mip + 0, a * xr.x); atomicAdd(mip + 1, a * xr.y);
    atomicAdd(mip + 2, a * xr.z); atomicAdd(mip + 3, a * xr.w);
    atomicAdd(mop + 0, a * xc.x); atomicAdd(mop + 1, a * xc.y);
    atomicAdd(mop + 2, a * xc.z); atomicAdd(mop + 3, a * xc.w);
}

// ---- fused MLP (unchanged) ----
__global__ __launch_bounds__(256) void mlp_kernel(
    const float* __restrict__ mi, const float* __restrict__ mo,
    const float* __restrict__ x,
    const float* __restrict__ W1, const float* __restrict__ b1,
    const float* __restrict__ W2, const float* __restrict__ b2,
    float* __restrict__ out, int N, int ngroups)
{
    __shared__ float sW1[96 * 64];
    __shared__ float sW2[64 * 64];
    __shared__ float sM[4][96];
    __shared__ float sh[4][64];

    for (int i = threadIdx.x; i < 96 * 64; i += 256) sW1[i] = W1[i];
    for (int i = threadIdx.x; i < 64 * 64; i += 256) sW2[i] = W2[i];
    __syncthreads();

    int nl = threadIdx.x >> 6;
    int o  = threadIdx.x & 63;
    float bias1 = b1[o];
    float bias2 = b2[o];

    for (int g = blockIdx.x; g < ngroups; g += gridDim.x) {
        int node0 = g * 4;
        for (int i = threadIdx.x; i < 4 * 96; i += 256) {
            int n_local = i / 96;
            int kk = i - n_local * 96;
            int node = node0 + n_local;
            float v = 0.0f;
            if (node < N) {
                if (kk < 32)      v = mi[(long long)node * 32 + kk];
                else if (kk < 64) v = mo[(long long)node * 32 + (kk - 32)];
                else              v = x [(long long)node * 32 + (kk - 64)];
            }
            sM[n_local][kk] = v;
        }
        __syncthreads();

        float acc1 = bias1;
        #pragma unroll
        for (int kk = 0; kk < 96; ++kk)
            acc1 = fmaf(sM[nl][kk], sW1[kk * 64 + o], acc1);
        sh[nl][o] = tanhf(acc1);
        __syncthreads();

        float acc2 = bias2;
        #pragma unroll
        for (int kk = 0; kk < 64; ++kk)
            acc2 = fmaf(sh[nl][kk], sW2[kk * 64 + o], acc2);

        int node = node0 + nl;
        if (node < N)
            out[(long long)node * 64 + o] = tanhf(acc2);
        __syncthreads();
    }
}

extern "C" void kernel_launch(void* const* d_in, const int* in_sizes, int n_in,
                              void* d_out, int out_size, void* d_ws, size_t ws_size,
                              hipStream_t stream) {
    const float* x  = (const float*)d_in[0];
    const int*   ei = (const int*)  d_in[1];
    const float* ea = (const float*)d_in[2];
    const float* W1 = (const float*)d_in[3];
    const float* b1 = (const float*)d_in[4];
    const float* W2 = (const float*)d_in[5];
    const float* b2 = (const float*)d_in[6];
    float* out = (float*)d_out;

    int N    = in_sizes[0] / DFEAT;              // 100000
    int E    = in_sizes[2];                      // 1600000
    int NK   = 2 * N;
    int NBIN = (NK + KEYS_PER_BIN - 1) / KEYS_PER_BIN;   // 1563
    int nPB  = (E + EPB - 1) / EPB;                      // 782

    float* mi = (float*)d_ws;
    float* mo = mi + (size_t)N * DFEAT;

    size_t paySlots = (size_t)2 * E + NBIN;      // + even-padding slack
    size_t need = (size_t)N * DFEAT * 2 * 4      // mi, mo
                + paySlots * 8                   // records
                + (size_t)nPB * NBIN * 4 * 2     // blockhist + ofsT
                + (size_t)NBIN * 4 * 2 + 64;     // bintotal + binbase

    if (ws_size >= need && N <= (1 << 17) && NBIN <= MAXBIN) {
        u64* pay       = (u64*)(mo + (size_t)N * DFEAT);
        int* blockhist = (int*)(pay + paySlots);
        int* ofsT      = blockhist + (size_t)nPB * NBIN;
        int* bintotal  = ofsT + (size_t)nPB * NBIN;
        int* binbase   = bintotal + NBIN;

        hist_part<<<nPB, 256, 0, stream>>>(ei, blockhist, E, NBIN);
        colscan<<<NBIN, 64, 0, stream>>>(blockhist, ofsT, bintotal, nPB, NBIN);
        scan_bins<<<1, 1024, 0, stream>>>(bintotal, binbase, NBIN);
        partition_kernel<<<nPB, 256, 0, stream>>>(ei, ea, ofsT, binbase,
                                                  pay, E, NBIN, nPB);
        accum_sortgather<<<NBIN, 256, 0, stream>>>(x, binbase, bintotal, pay,
                                                   mi, mo, NK);
    } else {
        hipMemsetAsync(d_ws, 0, (size_t)N * DFEAT * 2 * sizeof(float), stream);
        long long total = (long long)E * 8;
        int nblocks = (int)((total + 255) / 256);
        edge_scatter_kernel<<<nblocks, 256, 0, stream>>>(x, ei, ea, mi, mo, E);
    }

    int ngroups = (N + 3) / 4;
    int mlpblocks = ngroups < 2048 ? ngroups : 2048;
    mlp_kernel<<<mlpblocks, 256, 0, stream>>>(mi, mo, x, W1, b1, W2, b2, out, N, ngroups);
}

// Round 10
// 285.859 us; speedup vs baseline: 4.3350x; 1.1314x over previous
//
#include <hip/hip_runtime.h>
#include <hip/hip_bf16.h>

// NodeNetwork: mi = segsum(ea*x[row] -> col), mo = segsum(ea*x[col] -> row)
// out = tanh(tanh([mi|mo|x] @ W1 + b1) @ W2 + b2)
// N=100000, D=32, O=64, E=1600000
//
// R10: fix R9's silent readlane type bug. __builtin_amdgcn_readlane is
// int(int,int); passing float inserted fptosi/sitofp conversions that
// truncated every broadcast operand (absmax 1.25). Now bitcast via
// __float_as_int / __int_as_float (free). MLP structure otherwise as R9:
// weights in VGPRs, readlane->SGPR operand into v_fma, no LDS.
// Edge pipeline unchanged from R8 (accum 132us, total 323us with old MLP).

#define DFEAT 32
#define OFEAT 64
#define EPB   2048            // edges per partition block -> 4096 records
#define KEYS_PER_BIN 128      // partition bin = key >> 7 ; lkey = key & 127
#define MAXBIN 2048
#define CAP   3072            // records staged per chunk (24 KB)

typedef unsigned long long u64;

__device__ __forceinline__ float rdlane(float v, int l) {
    return __int_as_float(__builtin_amdgcn_readlane(__float_as_int(v), l));
}

// ---- A. per-block histogram over bins ----
__global__ __launch_bounds__(256) void hist_part(
    const int* __restrict__ ei, int* __restrict__ blockhist, int E, int NBIN)
{
    __shared__ int lh[MAXBIN];
    int blk = blockIdx.x;
    for (int i = threadIdx.x; i < NBIN; i += 256) lh[i] = 0;
    __syncthreads();
    int e0 = blk * EPB;
    #pragma unroll
    for (int j = 0; j < 8; ++j) {
        int e = e0 + j * 256 + threadIdx.x;
        if (e < E) {
            int r = ei[e], c = ei[E + e];
            atomicAdd(&lh[(2 * c) >> 7], 1);
            atomicAdd(&lh[(2 * r + 1) >> 7], 1);
        }
    }
    __syncthreads();
    for (int i = threadIdx.x; i < NBIN; i += 256)
        blockhist[(long long)blk * NBIN + i] = lh[i];
}

// ---- B. column scan: per-bin prefix over blocks -> ofsT, bintotal ----
__global__ __launch_bounds__(64) void colscan(
    const int* __restrict__ blockhist, int* __restrict__ ofsT,
    int* __restrict__ bintotal, int nPB, int NBIN)
{
    int bin  = blockIdx.x;
    int lane = threadIdx.x;
    int run = 0;
    for (int b0 = 0; b0 < nPB; b0 += 64) {
        int b = b0 + lane;
        int v = (b < nPB) ? blockhist[(long long)b * NBIN + bin] : 0;
        int s = v;
        #pragma unroll
        for (int d = 1; d < 64; d <<= 1) {
            int t = __shfl_up(s, d, 64);
            if (lane >= d) s += t;
        }
        if (b < nPB) ofsT[(long long)bin * nPB + b] = s - v + run;
        run += __shfl(s, 63, 64);
    }
    if (lane == 0) bintotal[bin] = run;
}

// ---- C. exclusive scan of (even-padded) bin totals, up to 2048 bins ----
__global__ __launch_bounds__(1024) void scan_bins(
    const int* __restrict__ bintotal, int* __restrict__ binbase, int NBIN)
{
    __shared__ int s[1024];
    int t = threadIdx.x;
    int i0 = 2 * t, i1 = 2 * t + 1;
    int p0 = (i0 < NBIN) ? ((bintotal[i0] + 1) & ~1) : 0;  // even-pad -> 16B align
    int p1 = (i1 < NBIN) ? ((bintotal[i1] + 1) & ~1) : 0;
    int v = p0 + p1;
    s[t] = v;
    __syncthreads();
    for (int o = 1; o < 1024; o <<= 1) {
        int u = (t >= o) ? s[t - o] : 0;
        __syncthreads();
        s[t] += u;
        __syncthreads();
    }
    int excl = s[t] - v;
    if (i0 < NBIN) binbase[i0] = excl;
    if (i1 < NBIN) binbase[i1] = excl + p0;
}

// ---- D. partition: LDS reorder + coalesced flush ----
__global__ __launch_bounds__(256) void partition_kernel(
    const int* __restrict__ ei, const float* __restrict__ ea,
    const int* __restrict__ ofsT, const int* __restrict__ binbase,
    u64* __restrict__ pay, int E, int NBIN, int nPB)
{
    __shared__ int lofs[MAXBIN + 1];
    __shared__ int lcur[MAXBIN];
    __shared__ int lbase[MAXBIN];
    __shared__ u64 stag[2 * EPB];        // 32 KB
    int blk = blockIdx.x, tid = threadIdx.x;
    int e0 = blk * EPB;

    for (int i = tid; i < NBIN; i += 256) lcur[i] = 0;
    __syncthreads();

    // pass 1: load edges (kept in regs), LDS histogram
    int r[8], c[8]; float a[8]; bool valid[8];
    #pragma unroll
    for (int j = 0; j < 8; ++j) {
        int e = e0 + j * 256 + tid;
        valid[j] = (e < E);
        if (valid[j]) {
            r[j] = ei[e]; c[j] = ei[E + e]; a[j] = ea[e];
            atomicAdd(&lcur[(2 * c[j]) >> 7], 1);
            atomicAdd(&lcur[(2 * r[j] + 1) >> 7], 1);
        }
    }
    __syncthreads();

    // wave 0: exclusive scan lcur -> lofs
    if (tid < 64) {
        int runc = 0;
        for (int b0 = 0; b0 < NBIN; b0 += 64) {
            int i = b0 + tid;
            int v = (i < NBIN) ? lcur[i] : 0;
            int s = v;
            #pragma unroll
            for (int d = 1; d < 64; d <<= 1) {
                int t2 = __shfl_up(s, d, 64);
                if (tid >= d) s += t2;
            }
            if (i < NBIN) lofs[i] = s - v + runc;
            runc += __shfl(s, 63, 64);
        }
        if (tid == 0) lofs[NBIN] = runc;
    }
    __syncthreads();

    // reset tickets, compute global bases for this block
    for (int i = tid; i < NBIN; i += 256) {
        lcur[i] = 0;
        lbase[i] = binbase[i] + ofsT[(long long)i * nPB + blk];
    }
    __syncthreads();

    // pass 2: place records into LDS staging (sorted by bin)
    #pragma unroll
    for (int j = 0; j < 8; ++j) {
        if (valid[j]) {
            unsigned int ab = (unsigned int)__float_as_int(a[j]);
            {
                int key = 2 * c[j]; int bin = key >> 7;      // mi: src = r
                int t2 = atomicAdd(&lcur[bin], 1);
                stag[lofs[bin] + t2] = ((u64)ab << 32) |
                    (unsigned int)(r[j] | ((key & 127) << 17));
            }
            {
                int key = 2 * r[j] + 1; int bin = key >> 7;  // mo: src = c
                int t2 = atomicAdd(&lcur[bin], 1);
                stag[lofs[bin] + t2] = ((u64)ab << 32) |
                    (unsigned int)(c[j] | ((key & 127) << 17));
            }
        }
    }
    __syncthreads();

    // flush: contiguous runs per bin -> mostly full-line global writes
    int total = lofs[NBIN];
    for (int i = tid; i < total; i += 256) {
        int lo = 0, hi = NBIN;               // lofs[lo] <= i < lofs[hi]
        while (hi - lo > 1) {
            int mid = (lo + hi) >> 1;
            if (lofs[mid] <= i) lo = mid; else hi = mid;
        }
        pay[lbase[lo] + (i - lofs[lo])] = stag[i];
    }
}

// ---- E. accum: in-LDS key sort + per-key dual-chain register gather ----
__global__ __launch_bounds__(256) void accum_sortgather(
    const float* __restrict__ x,
    const int* __restrict__ binbase, const int* __restrict__ bintotal,
    const u64* __restrict__ pay,
    float* __restrict__ mi, float* __restrict__ mo, int NK)
{
    __shared__ u64 srec[CAP];                 // 24 KB, records sorted by key
    __shared__ int lcnt[KEYS_PER_BIN];
    __shared__ int lofs[KEYS_PER_BIN];
    __shared__ int lcur[KEYS_PER_BIN];

    int b = blockIdx.x, tid = threadIdx.x;
    int base = binbase[b];
    int n    = bintotal[b];
    int wid  = tid >> 6;        // 0..3: wave -> owns keys [wid*32, wid*32+32)
    int lane = tid & 63;
    int half = lane >> 5;       // dual record chains per half-wave
    int feat = lane & 31;

    float acc0[16], acc1[16];
    #pragma unroll
    for (int p = 0; p < 16; ++p) { acc0[p] = 0.0f; acc1[p] = 0.0f; }

    for (int c0 = 0; c0 < n; c0 += CAP) {
        int cn = min(n - c0, CAP);
        if (tid < KEYS_PER_BIN) lcnt[tid] = 0;
        __syncthreads();
        // count keys in this chunk
        for (int i = tid; i < cn; i += 256)
            atomicAdd(&lcnt[((int)pay[base + c0 + i] >> 17) & 127], 1);
        __syncthreads();
        // exclusive scan of 128 counters (wave 0, 2 keys/lane)
        if (tid < 64) {
            int v0 = lcnt[2 * tid], v1 = lcnt[2 * tid + 1];
            int s = v0 + v1, ss = s;
            #pragma unroll
            for (int d = 1; d < 64; d <<= 1) {
                int t = __shfl_up(ss, d, 64);
                if (tid >= d) ss += t;
            }
            int excl = ss - s;
            lofs[2 * tid] = excl;      lofs[2 * tid + 1] = excl + v0;
            lcur[2 * tid] = excl;      lcur[2 * tid + 1] = excl + v0;
        }
        __syncthreads();
        // place records sorted by key
        for (int i = tid; i < cn; i += 256) {
            u64 v = pay[base + c0 + i];              // L2-hot re-read
            int t2 = atomicAdd(&lcur[((int)v >> 17) & 127], 1);
            srec[t2] = v;
        }
        __syncthreads();

        // gather: 16 key-pairs per wave, two independent chains per half
        #pragma unroll
        for (int p = 0; p < 16; ++p) {
            int kA = wid * 32 + 2 * p;
            int kB = kA + 1;
            int sA = lofs[kA], eA = sA + lcnt[kA];
            int sB = lofs[kB], eB = sB + lcnt[kB];
            int iA = sA + half, iB = sB + half;
            float aA = acc0[p], aB = acc1[p];
            while (iA < eA && iB < eB) {
                u64 ra = srec[iA], rb = srec[iB];
                float xa = x[(long long)((int)ra & 0x1FFFF) * DFEAT + feat];
                float xb = x[(long long)((int)rb & 0x1FFFF) * DFEAT + feat];
                aA = fmaf(__int_as_float((int)(ra >> 32)), xa, aA);
                aB = fmaf(__int_as_float((int)(rb >> 32)), xb, aB);
                iA += 2; iB += 2;
            }
            while (iA < eA) {
                u64 ra = srec[iA];
                float xa = x[(long long)((int)ra & 0x1FFFF) * DFEAT + feat];
                aA = fmaf(__int_as_float((int)(ra >> 32)), xa, aA);
                iA += 2;
            }
            while (iB < eB) {
                u64 rb = srec[iB];
                float xb = x[(long long)((int)rb & 0x1FFFF) * DFEAT + feat];
                aB = fmaf(__int_as_float((int)(rb >> 32)), xb, aB);
                iB += 2;
            }
            acc0[p] = aA; acc1[p] = aB;
        }
        __syncthreads();    // protect srec/lcnt before next chunk
    }

    // combine halves; lanes 0-31 write key kA's row, lanes 32-63 key kB's
    int key0 = b * KEYS_PER_BIN + wid * 32;
    #pragma unroll
    for (int p = 0; p < 16; ++p) {
        float tA = acc0[p] + __shfl_xor(acc0[p], 32, 64);
        float tB = acc1[p] + __shfl_xor(acc1[p], 32, 64);
        int gk = key0 + 2 * p + half;
        float v = half ? tB : tA;
        if (gk < NK) {
            int node = gk >> 1;
            float* dst = (gk & 1) ? mo : mi;
            dst[(long long)node * DFEAT + feat] = v;
        }
    }
}

// ---- fallback: direct atomic scatter (ws too small / N too big) ----
__global__ __launch_bounds__(256) void edge_scatter_kernel(
    const float* __restrict__ x, const int* __restrict__ ei,
    const float* __restrict__ ea,
    float* __restrict__ mi, float* __restrict__ mo, int E)
{
    long long tid = (long long)blockIdx.x * blockDim.x + threadIdx.x;
    long long total = (long long)E * 8;
    if (tid >= total) return;
    int e = (int)(tid >> 3);
    int q = (int)(tid & 7);
    int r = ei[e];
    int c = ei[E + e];
    float a = ea[e];
    const float4* x4 = (const float4*)x;
    float4 xr = x4[(long long)r * 8 + q];
    float4 xc = x4[(long long)c * 8 + q];
    float* mip = mi + (long long)c * DFEAT + q * 4;
    float* mop = mo + (long long)r * DFEAT + q * 4;
    atomicAdd(mip + 0, a * xr.x); atomicAdd(mip + 1, a * xr.y);
    atomicAdd(mip + 2, a * xr.z); atomicAdd(mip + 3, a * xr.w);
    atomicAdd(mop + 0, a * xc.x); atomicAdd(mop + 1, a * xc.y);
    atomicAdd(mop + 2, a * xc.z); atomicAdd(mop + 3, a * xc.w);
}

// ---- F. MLP: weights in VGPRs, operands broadcast via v_readlane ----
__global__ __launch_bounds__(256) void mlp_reg_kernel(
    const float* __restrict__ mi, const float* __restrict__ mo,
    const float* __restrict__ x,
    const float* __restrict__ W1, const float* __restrict__ b1,
    const float* __restrict__ W2, const float* __restrict__ b2,
    float* __restrict__ out, int N)
{
    int o   = threadIdx.x & 63;     // lane = output index
    int wid = threadIdx.x >> 6;     // wave within block

    float w1r[96], w2r[64];
    #pragma unroll
    for (int k = 0; k < 96; ++k) w1r[k] = W1[k * 64 + o];
    #pragma unroll
    for (int k = 0; k < 64; ++k) w2r[k] = W2[k * 64 + o];
    float bias1 = b1[o];
    float bias2 = b2[o];

    int stride = gridDim.x * 4;
    for (int node = blockIdx.x * 4 + wid; node < N; node += stride) {
        long long nb = (long long)node * DFEAT;
        // m01: lanes 0-31 = mi[node][o], lanes 32-63 = mo[node][o-32]
        float m01 = (o < 32) ? mi[nb + o] : mo[nb + (o - 32)];
        // m2v: lanes 0-31 = x[node][o]
        float m2v = (o < 32) ? x[nb + o] : 0.0f;

        float a0 = bias1, a1 = 0.0f, a2 = 0.0f, a3 = 0.0f;
        #pragma unroll
        for (int k = 0; k < 64; k += 4) {
            a0 = fmaf(rdlane(m01, k + 0), w1r[k + 0], a0);
            a1 = fmaf(rdlane(m01, k + 1), w1r[k + 1], a1);
            a2 = fmaf(rdlane(m01, k + 2), w1r[k + 2], a2);
            a3 = fmaf(rdlane(m01, k + 3), w1r[k + 3], a3);
        }
        #pragma unroll
        for (int k = 0; k < 32; k += 4) {
            a0 = fmaf(rdlane(m2v, k + 0), w1r[64 + k + 0], a0);
            a1 = fmaf(rdlane(m2v, k + 1), w1r[64 + k + 1], a1);
            a2 = fmaf(rdlane(m2v, k + 2), w1r[64 + k + 2], a2);
            a3 = fmaf(rdlane(m2v, k + 3), w1r[64 + k + 3], a3);
        }
        float h = tanhf(((a0 + a1) + (a2 + a3)));

        float c0 = bias2, c1 = 0.0f, c2 = 0.0f, c3 = 0.0f;
        #pragma unroll
        for (int k = 0; k < 64; k += 4) {
            c0 = fmaf(rdlane(h, k + 0), w2r[k + 0], c0);
            c1 = fmaf(rdlane(h, k + 1), w2r[k + 1], c1);
            c2 = fmaf(rdlane(h, k + 2), w2r[k + 2], c2);
            c3 = fmaf(rdlane(h, k + 3), w2r[k + 3], c3);
        }
        out[(long long)node * OFEAT + o] = tanhf(((c0 + c1) + (c2 + c3)));
    }
}

extern "C" void kernel_launch(void* const* d_in, const int* in_sizes, int n_in,
                              void* d_out, int out_size, void* d_ws, size_t ws_size,
                              hipStream_t stream) {
    const float* x  = (const float*)d_in[0];
    const int*   ei = (const int*)  d_in[1];
    const float* ea = (const float*)d_in[2];
    const float* W1 = (const float*)d_in[3];
    const float* b1 = (const float*)d_in[4];
    const float* W2 = (const float*)d_in[5];
    const float* b2 = (const float*)d_in[6];
    float* out = (float*)d_out;

    int N    = in_sizes[0] / DFEAT;              // 100000
    int E    = in_sizes[2];                      // 1600000
    int NK   = 2 * N;
    int NBIN = (NK + KEYS_PER_BIN - 1) / KEYS_PER_BIN;   // 1563
    int nPB  = (E + EPB - 1) / EPB;                      // 782

    float* mi = (float*)d_ws;
    float* mo = mi + (size_t)N * DFEAT;

    size_t paySlots = (size_t)2 * E + NBIN;      // + even-padding slack
    size_t need = (size_t)N * DFEAT * 2 * 4      // mi, mo
                + paySlots * 8                   // records
                + (size_t)nPB * NBIN * 4 * 2     // blockhist + ofsT
                + (size_t)NBIN * 4 * 2 + 64;     // bintotal + binbase

    if (ws_size >= need && N <= (1 << 17) && NBIN <= MAXBIN) {
        u64* pay       = (u64*)(mo + (size_t)N * DFEAT);
        int* blockhist = (int*)(pay + paySlots);
        int* ofsT      = blockhist + (size_t)nPB * NBIN;
        int* bintotal  = ofsT + (size_t)nPB * NBIN;
        int* binbase   = bintotal + NBIN;

        hist_part<<<nPB, 256, 0, stream>>>(ei, blockhist, E, NBIN);
        colscan<<<NBIN, 64, 0, stream>>>(blockhist, ofsT, bintotal, nPB, NBIN);
        scan_bins<<<1, 1024, 0, stream>>>(bintotal, binbase, NBIN);
        partition_kernel<<<nPB, 256, 0, stream>>>(ei, ea, ofsT, binbase,
                                                  pay, E, NBIN, nPB);
        accum_sortgather<<<NBIN, 256, 0, stream>>>(x, binbase, bintotal, pay,
                                                   mi, mo, NK);
    } else {
        hipMemsetAsync(d_ws, 0, (size_t)N * DFEAT * 2 * sizeof(float), stream);
        long long total = (long long)E * 8;
        int nblocks = (int)((total + 255) / 256);
        edge_scatter_kernel<<<nblocks, 256, 0, stream>>>(x, ei, ea, mi, mo, E);
    }

    mlp_reg_kernel<<<512, 256, 0, stream>>>(mi, mo, x, W1, b1, W2, b2, out, N);
}

// Round 11
// 257.026 us; speedup vs baseline: 4.8213x; 1.1122x over previous
//
#include <hip/hip_runtime.h>
#include <hip/hip_bf16.h>

// NodeNetwork: mi = segsum(ea*x[row] -> col), mo = segsum(ea*x[col] -> row)
// out = tanh(tanh([mi|mo|x] @ W1 + b1) @ W2 + b2)
// N=100000, D=32, O=64, E=1600000
//
// R11: accum gather widened to QUAD chains per half-wave (4 keys per step,
// 4 independent x-loads in flight; R10 dual-chain was MLP-limited at
// VALUBusy 17%, 2 loads/wave). Partition flush: binary search (11 LDS reads
// per record) replaced by u16 bin tag written at place time.
// R10 baseline: 286us total, accum 133us.

#define DFEAT 32
#define OFEAT 64
#define EPB   2048            // edges per partition block -> 4096 records
#define KEYS_PER_BIN 128      // partition bin = key >> 7 ; lkey = key & 127
#define MAXBIN 2048
#define CAP   3072            // records staged per chunk (24 KB)

typedef unsigned long long u64;

__device__ __forceinline__ float rdlane(float v, int l) {
    return __int_as_float(__builtin_amdgcn_readlane(__float_as_int(v), l));
}

// ---- A. per-block histogram over bins ----
__global__ __launch_bounds__(256) void hist_part(
    const int* __restrict__ ei, int* __restrict__ blockhist, int E, int NBIN)
{
    __shared__ int lh[MAXBIN];
    int blk = blockIdx.x;
    for (int i = threadIdx.x; i < NBIN; i += 256) lh[i] = 0;
    __syncthreads();
    int e0 = blk * EPB;
    #pragma unroll
    for (int j = 0; j < 8; ++j) {
        int e = e0 + j * 256 + threadIdx.x;
        if (e < E) {
            int r = ei[e], c = ei[E + e];
            atomicAdd(&lh[(2 * c) >> 7], 1);
            atomicAdd(&lh[(2 * r + 1) >> 7], 1);
        }
    }
    __syncthreads();
    for (int i = threadIdx.x; i < NBIN; i += 256)
        blockhist[(long long)blk * NBIN + i] = lh[i];
}

// ---- B. column scan: per-bin prefix over blocks -> ofsT, bintotal ----
__global__ __launch_bounds__(64) void colscan(
    const int* __restrict__ blockhist, int* __restrict__ ofsT,
    int* __restrict__ bintotal, int nPB, int NBIN)
{
    int bin  = blockIdx.x;
    int lane = threadIdx.x;
    int run = 0;
    for (int b0 = 0; b0 < nPB; b0 += 64) {
        int b = b0 + lane;
        int v = (b < nPB) ? blockhist[(long long)b * NBIN + bin] : 0;
        int s = v;
        #pragma unroll
        for (int d = 1; d < 64; d <<= 1) {
            int t = __shfl_up(s, d, 64);
            if (lane >= d) s += t;
        }
        if (b < nPB) ofsT[(long long)bin * nPB + b] = s - v + run;
        run += __shfl(s, 63, 64);
    }
    if (lane == 0) bintotal[bin] = run;
}

// ---- C. exclusive scan of (even-padded) bin totals, up to 2048 bins ----
__global__ __launch_bounds__(1024) void scan_bins(
    const int* __restrict__ bintotal, int* __restrict__ binbase, int NBIN)
{
    __shared__ int s[1024];
    int t = threadIdx.x;
    int i0 = 2 * t, i1 = 2 * t + 1;
    int p0 = (i0 < NBIN) ? ((bintotal[i0] + 1) & ~1) : 0;  // even-pad -> 16B align
    int p1 = (i1 < NBIN) ? ((bintotal[i1] + 1) & ~1) : 0;
    int v = p0 + p1;
    s[t] = v;
    __syncthreads();
    for (int o = 1; o < 1024; o <<= 1) {
        int u = (t >= o) ? s[t - o] : 0;
        __syncthreads();
        s[t] += u;
        __syncthreads();
    }
    int excl = s[t] - v;
    if (i0 < NBIN) binbase[i0] = excl;
    if (i1 < NBIN) binbase[i1] = excl + p0;
}

// ---- D. partition: LDS reorder + coalesced flush (binof tag) ----
__global__ __launch_bounds__(256) void partition_kernel(
    const int* __restrict__ ei, const float* __restrict__ ea,
    const int* __restrict__ ofsT, const int* __restrict__ binbase,
    u64* __restrict__ pay, int E, int NBIN, int nPB)
{
    __shared__ int lofs[MAXBIN + 1];
    __shared__ int lcur[MAXBIN];
    __shared__ int lbase[MAXBIN];
    __shared__ u64 stag[2 * EPB];             // 32 KB
    __shared__ unsigned short binof[2 * EPB]; // 8 KB
    int blk = blockIdx.x, tid = threadIdx.x;
    int e0 = blk * EPB;

    for (int i = tid; i < NBIN; i += 256) lcur[i] = 0;
    __syncthreads();

    // pass 1: load edges (kept in regs), LDS histogram
    int r[8], c[8]; float a[8]; bool valid[8];
    #pragma unroll
    for (int j = 0; j < 8; ++j) {
        int e = e0 + j * 256 + tid;
        valid[j] = (e < E);
        if (valid[j]) {
            r[j] = ei[e]; c[j] = ei[E + e]; a[j] = ea[e];
            atomicAdd(&lcur[(2 * c[j]) >> 7], 1);
            atomicAdd(&lcur[(2 * r[j] + 1) >> 7], 1);
        }
    }
    __syncthreads();

    // wave 0: exclusive scan lcur -> lofs
    if (tid < 64) {
        int runc = 0;
        for (int b0 = 0; b0 < NBIN; b0 += 64) {
            int i = b0 + tid;
            int v = (i < NBIN) ? lcur[i] : 0;
            int s = v;
            #pragma unroll
            for (int d = 1; d < 64; d <<= 1) {
                int t2 = __shfl_up(s, d, 64);
                if (tid >= d) s += t2;
            }
            if (i < NBIN) lofs[i] = s - v + runc;
            runc += __shfl(s, 63, 64);
        }
        if (tid == 0) lofs[NBIN] = runc;
    }
    __syncthreads();

    // reset tickets, compute global bases for this block
    for (int i = tid; i < NBIN; i += 256) {
        lcur[i] = 0;
        lbase[i] = binbase[i] + ofsT[(long long)i * nPB + blk];
    }
    __syncthreads();

    // pass 2: place records into LDS staging (sorted by bin) + bin tag
    #pragma unroll
    for (int j = 0; j < 8; ++j) {
        if (valid[j]) {
            unsigned int ab = (unsigned int)__float_as_int(a[j]);
            {
                int key = 2 * c[j]; int bin = key >> 7;      // mi: src = r
                int t2 = atomicAdd(&lcur[bin], 1);
                int pos = lofs[bin] + t2;
                stag[pos] = ((u64)ab << 32) |
                    (unsigned int)(r[j] | ((key & 127) << 17));
                binof[pos] = (unsigned short)bin;
            }
            {
                int key = 2 * r[j] + 1; int bin = key >> 7;  // mo: src = c
                int t2 = atomicAdd(&lcur[bin], 1);
                int pos = lofs[bin] + t2;
                stag[pos] = ((u64)ab << 32) |
                    (unsigned int)(c[j] | ((key & 127) << 17));
                binof[pos] = (unsigned short)bin;
            }
        }
    }
    __syncthreads();

    // flush: contiguous runs per bin -> mostly full-line global writes
    int total = lofs[NBIN];
    for (int i = tid; i < total; i += 256) {
        int bn = binof[i];
        pay[lbase[bn] + (i - lofs[bn])] = stag[i];
    }
}

// ---- E. accum: in-LDS key sort + quad-chain register gather ----
__global__ __launch_bounds__(256) void accum_sortgather(
    const float* __restrict__ x,
    const int* __restrict__ binbase, const int* __restrict__ bintotal,
    const u64* __restrict__ pay,
    float* __restrict__ mi, float* __restrict__ mo, int NK)
{
    __shared__ u64 srec[CAP];                 // 24 KB, records sorted by key
    __shared__ int lcnt[KEYS_PER_BIN];
    __shared__ int lofs[KEYS_PER_BIN];
    __shared__ int lcur[KEYS_PER_BIN];

    int b = blockIdx.x, tid = threadIdx.x;
    int base = binbase[b];
    int n    = bintotal[b];
    int wid  = tid >> 6;        // 0..3: wave -> owns keys [wid*32, wid*32+32)
    int lane = tid & 63;
    int half = lane >> 5;       // records strided by 2 across halves
    int feat = lane & 31;

    float accA[8], accB[8], accC[8], accD[8];
    #pragma unroll
    for (int p = 0; p < 8; ++p) {
        accA[p] = 0.0f; accB[p] = 0.0f; accC[p] = 0.0f; accD[p] = 0.0f;
    }

    for (int c0 = 0; c0 < n; c0 += CAP) {
        int cn = min(n - c0, CAP);
        if (tid < KEYS_PER_BIN) lcnt[tid] = 0;
        __syncthreads();
        // count keys in this chunk
        for (int i = tid; i < cn; i += 256)
            atomicAdd(&lcnt[((int)pay[base + c0 + i] >> 17) & 127], 1);
        __syncthreads();
        // exclusive scan of 128 counters (wave 0, 2 keys/lane)
        if (tid < 64) {
            int v0 = lcnt[2 * tid], v1 = lcnt[2 * tid + 1];
            int s = v0 + v1, ss = s;
            #pragma unroll
            for (int d = 1; d < 64; d <<= 1) {
                int t = __shfl_up(ss, d, 64);
                if (tid >= d) ss += t;
            }
            int excl = ss - s;
            lofs[2 * tid] = excl;      lofs[2 * tid + 1] = excl + v0;
            lcur[2 * tid] = excl;      lcur[2 * tid + 1] = excl + v0;
        }
        __syncthreads();
        // place records sorted by key
        for (int i = tid; i < cn; i += 256) {
            u64 v = pay[base + c0 + i];              // L2-hot re-read
            int t2 = atomicAdd(&lcur[((int)v >> 17) & 127], 1);
            srec[t2] = v;
        }
        __syncthreads();

        // gather: 8 quads of keys per wave; 4 independent chains per half
        #pragma unroll
        for (int p = 0; p < 8; ++p) {
            int kb = wid * 32 + 4 * p;
            int s0 = lofs[kb + 0], e0 = s0 + lcnt[kb + 0];
            int s1 = lofs[kb + 1], e1 = s1 + lcnt[kb + 1];
            int s2 = lofs[kb + 2], e2 = s2 + lcnt[kb + 2];
            int s3 = lofs[kb + 3], e3 = s3 + lcnt[kb + 3];
            int i0 = s0 + half, i1 = s1 + half, i2 = s2 + half, i3 = s3 + half;
            float a0 = accA[p], a1 = accB[p], a2 = accC[p], a3 = accD[p];
            while (i0 < e0 && i1 < e1 && i2 < e2 && i3 < e3) {
                u64 r0 = srec[i0], r1 = srec[i1], r2 = srec[i2], r3 = srec[i3];
                float x0 = x[(long long)((int)r0 & 0x1FFFF) * DFEAT + feat];
                float x1 = x[(long long)((int)r1 & 0x1FFFF) * DFEAT + feat];
                float x2 = x[(long long)((int)r2 & 0x1FFFF) * DFEAT + feat];
                float x3 = x[(long long)((int)r3 & 0x1FFFF) * DFEAT + feat];
                a0 = fmaf(__int_as_float((int)(r0 >> 32)), x0, a0);
                a1 = fmaf(__int_as_float((int)(r1 >> 32)), x1, a1);
                a2 = fmaf(__int_as_float((int)(r2 >> 32)), x2, a2);
                a3 = fmaf(__int_as_float((int)(r3 >> 32)), x3, a3);
                i0 += 2; i1 += 2; i2 += 2; i3 += 2;
            }
            while (i0 < e0) {
                u64 rr = srec[i0];
                a0 = fmaf(__int_as_float((int)(rr >> 32)),
                          x[(long long)((int)rr & 0x1FFFF) * DFEAT + feat], a0);
                i0 += 2;
            }
            while (i1 < e1) {
                u64 rr = srec[i1];
                a1 = fmaf(__int_as_float((int)(rr >> 32)),
                          x[(long long)((int)rr & 0x1FFFF) * DFEAT + feat], a1);
                i1 += 2;
            }
            while (i2 < e2) {
                u64 rr = srec[i2];
                a2 = fmaf(__int_as_float((int)(rr >> 32)),
                          x[(long long)((int)rr & 0x1FFFF) * DFEAT + feat], a2);
                i2 += 2;
            }
            while (i3 < e3) {
                u64 rr = srec[i3];
                a3 = fmaf(__int_as_float((int)(rr >> 32)),
                          x[(long long)((int)rr & 0x1FFFF) * DFEAT + feat], a3);
                i3 += 2;
            }
            accA[p] = a0; accB[p] = a1; accC[p] = a2; accD[p] = a3;
        }
        __syncthreads();    // protect srec/lcnt before next chunk
    }

    // combine halves; half 0 writes keys 4p+0/1, half 1 writes 4p+2/3
    int key0 = b * KEYS_PER_BIN + wid * 32;
    #pragma unroll
    for (int p = 0; p < 8; ++p) {
        float t0 = accA[p] + __shfl_xor(accA[p], 32, 64);
        float t1 = accB[p] + __shfl_xor(accB[p], 32, 64);
        float t2 = accC[p] + __shfl_xor(accC[p], 32, 64);
        float t3 = accD[p] + __shfl_xor(accD[p], 32, 64);
        float vA = half ? t2 : t0;
        float vB = half ? t3 : t1;
        int gkA = key0 + 4 * p + (half ? 2 : 0);
        int gkB = gkA + 1;
        if (gkA < NK) {
            int node = gkA >> 1;
            ((gkA & 1) ? mo : mi)[(long long)node * DFEAT + feat] = vA;
        }
        if (gkB < NK) {
            int node = gkB >> 1;
            ((gkB & 1) ? mo : mi)[(long long)node * DFEAT + feat] = vB;
        }
    }
}

// ---- fallback: direct atomic scatter (ws too small / N too big) ----
__global__ __launch_bounds__(256) void edge_scatter_kernel(
    const float* __restrict__ x, const int* __restrict__ ei,
    const float* __restrict__ ea,
    float* __restrict__ mi, float* __restrict__ mo, int E)
{
    long long tid = (long long)blockIdx.x * blockDim.x + threadIdx.x;
    long long total = (long long)E * 8;
    if (tid >= total) return;
    int e = (int)(tid >> 3);
    int q = (int)(tid & 7);
    int r = ei[e];
    int c = ei[E + e];
    float a = ea[e];
    const float4* x4 = (const float4*)x;
    float4 xr = x4[(long long)r * 8 + q];
    float4 xc = x4[(long long)c * 8 + q];
    float* mip = mi + (long long)c * DFEAT + q * 4;
    float* mop = mo + (long long)r * DFEAT + q * 4;
    atomicAdd(mip + 0, a * xr.x); atomicAdd(mip + 1, a * xr.y);
    atomicAdd(mip + 2, a * xr.z); atomicAdd(mip + 3, a * xr.w);
    atomicAdd(mop + 0, a * xc.x); atomicAdd(mop + 1, a * xc.y);
    atomicAdd(mop + 2, a * xc.z); atomicAdd(mop + 3, a * xc.w);
}

// ---- F. MLP: weights in VGPRs, operands broadcast via v_readlane ----
__global__ __launch_bounds__(256) void mlp_reg_kernel(
    const float* __restrict__ mi, const float* __restrict__ mo,
    const float* __restrict__ x,
    const float* __restrict__ W1, const float* __restrict__ b1,
    const float* __restrict__ W2, const float* __restrict__ b2,
    float* __restrict__ out, int N)
{
    int o   = threadIdx.x & 63;     // lane = output index
    int wid = threadIdx.x >> 6;     // wave within block

    float w1r[96], w2r[64];
    #pragma unroll
    for (int k = 0; k < 96; ++k) w1r[k] = W1[k * 64 + o];
    #pragma unroll
    for (int k = 0; k < 64; ++k) w2r[k] = W2[k * 64 + o];
    float bias1 = b1[o];
    float bias2 = b2[o];

    int stride = gridDim.x * 4;
    for (int node = blockIdx.x * 4 + wid; node < N; node += stride) {
        long long nb = (long long)node * DFEAT;
        float m01 = (o < 32) ? mi[nb + o] : mo[nb + (o - 32)];
        float m2v = (o < 32) ? x[nb + o] : 0.0f;

        float a0 = bias1, a1 = 0.0f, a2 = 0.0f, a3 = 0.0f;
        #pragma unroll
        for (int k = 0; k < 64; k += 4) {
            a0 = fmaf(rdlane(m01, k + 0), w1r[k + 0], a0);
            a1 = fmaf(rdlane(m01, k + 1), w1r[k + 1], a1);
            a2 = fmaf(rdlane(m01, k + 2), w1r[k + 2], a2);
            a3 = fmaf(rdlane(m01, k + 3), w1r[k + 3], a3);
        }
        #pragma unroll
        for (int k = 0; k < 32; k += 4) {
            a0 = fmaf(rdlane(m2v, k + 0), w1r[64 + k + 0], a0);
            a1 = fmaf(rdlane(m2v, k + 1), w1r[64 + k + 1], a1);
            a2 = fmaf(rdlane(m2v, k + 2), w1r[64 + k + 2], a2);
            a3 = fmaf(rdlane(m2v, k + 3), w1r[64 + k + 3], a3);
        }
        float h = tanhf(((a0 + a1) + (a2 + a3)));

        float c0 = bias2, c1 = 0.0f, c2 = 0.0f, c3 = 0.0f;
        #pragma unroll
        for (int k = 0; k < 64; k += 4) {
            c0 = fmaf(rdlane(h, k + 0), w2r[k + 0], c0);
            c1 = fmaf(rdlane(h, k + 1), w2r[k + 1], c1);
            c2 = fmaf(rdlane(h, k + 2), w2r[k + 2], c2);
            c3 = fmaf(rdlane(h, k + 3), w2r[k + 3], c3);
        }
        out[(long long)node * OFEAT + o] = tanhf(((c0 + c1) + (c2 + c3)));
    }
}

extern "C" void kernel_launch(void* const* d_in, const int* in_sizes, int n_in,
                              void* d_out, int out_size, void* d_ws, size_t ws_size,
                              hipStream_t stream) {
    const float* x  = (const float*)d_in[0];
    const int*   ei = (const int*)  d_in[1];
    const float* ea = (const float*)d_in[2];
    const float* W1 = (const float*)d_in[3];
    const float* b1 = (const float*)d_in[4];
    const float* W2 = (const float*)d_in[5];
    const float* b2 = (const float*)d_in[6];
    float* out = (float*)d_out;

    int N    = in_sizes[0] / DFEAT;              // 100000
    int E    = in_sizes[2];                      // 1600000
    int NK   = 2 * N;
    int NBIN = (NK + KEYS_PER_BIN - 1) / KEYS_PER_BIN;   // 1563
    int nPB  = (E + EPB - 1) / EPB;                      // 782

    float* mi = (float*)d_ws;
    float* mo = mi + (size_t)N * DFEAT;

    size_t paySlots = (size_t)2 * E + NBIN;      // + even-padding slack
    size_t need = (size_t)N * DFEAT * 2 * 4      // mi, mo
                + paySlots * 8                   // records
                + (size_t)nPB * NBIN * 4 * 2     // blockhist + ofsT
                + (size_t)NBIN * 4 * 2 + 64;     // bintotal + binbase

    if (ws_size >= need && N <= (1 << 17) && NBIN <= MAXBIN) {
        u64* pay       = (u64*)(mo + (size_t)N * DFEAT);
        int* blockhist = (int*)(pay + paySlots);
        int* ofsT      = blockhist + (size_t)nPB * NBIN;
        int* bintotal  = ofsT + (size_t)nPB * NBIN;
        int* binbase   = bintotal + NBIN;

        hist_part<<<nPB, 256, 0, stream>>>(ei, blockhist, E, NBIN);
        colscan<<<NBIN, 64, 0, stream>>>(blockhist, ofsT, bintotal, nPB, NBIN);
        scan_bins<<<1, 1024, 0, stream>>>(bintotal, binbase, NBIN);
        partition_kernel<<<nPB, 256, 0, stream>>>(ei, ea, ofsT, binbase,
                                                  pay, E, NBIN, nPB);
        accum_sortgather<<<NBIN, 256, 0, stream>>>(x, binbase, bintotal, pay,
                                                   mi, mo, NK);
    } else {
        hipMemsetAsync(d_ws, 0, (size_t)N * DFEAT * 2 * sizeof(float), stream);
        long long total = (long long)E * 8;
        int nblocks = (int)((total + 255) / 256);
        edge_scatter_kernel<<<nblocks, 256, 0, stream>>>(x, ei, ea, mi, mo, E);
    }

    mlp_reg_kernel<<<512, 256, 0, stream>>>(mi, mo, x, W1, b1, W2, b2, out, N);
}